// Round 1
// baseline (609.100 us; speedup 1.0000x reference)
//
#include <hip/hip_runtime.h>
#include <hip/hip_bf16.h>
#include <cstdint>
#include <cstddef>

#define NN 50000
#define NE 800000

// ---------------- preprocessing ----------------

__global__ __launch_bounds__(256) void zero_i32(int* __restrict__ p, int n) {
    int i = blockIdx.x * 256 + threadIdx.x;
    if (i < n) p[i] = 0;
}

__global__ __launch_bounds__(256) void count_deg(const int* __restrict__ dst,
                                                 int* __restrict__ cnt, int E) {
    int e = blockIdx.x * 256 + threadIdx.x;
    if (e < E) atomicAdd(&cnt[dst[e]], 1);
}

// single-block exclusive scan over N counts -> rowptr, cursor
__global__ __launch_bounds__(1024) void scan_deg(const int* __restrict__ cnt,
                                                 int* __restrict__ rowptr,
                                                 int* __restrict__ cursor, int N) {
    __shared__ int s[1024];
    int t = threadIdx.x;
    int running = 0;
    for (int base = 0; base < N; base += 1024) {
        int v = (base + t < N) ? cnt[base + t] : 0;
        s[t] = v;
        __syncthreads();
        for (int off = 1; off < 1024; off <<= 1) {
            int add = (t >= off) ? s[t - off] : 0;
            __syncthreads();
            s[t] += add;
            __syncthreads();
        }
        int excl = s[t] - v;
        if (base + t < N) { rowptr[base + t] = running + excl; cursor[base + t] = running + excl; }
        int tot = s[1023];
        __syncthreads();
        running += tot;
    }
    if (t == 0) rowptr[N] = running;
}

__global__ __launch_bounds__(256) void calc_dinv(const int* __restrict__ cnt,
                                                 float* __restrict__ dinv, int N) {
    int i = blockIdx.x * 256 + threadIdx.x;
    if (i < N) dinv[i] = rsqrtf((float)cnt[i] + 1.0f);
}

__global__ __launch_bounds__(256) void scatter_csr(const int* __restrict__ src,
                                                   const int* __restrict__ dst,
                                                   int* __restrict__ cursor,
                                                   int* __restrict__ csr, int E) {
    int e = blockIdx.x * 256 + threadIdx.x;
    if (e < E) {
        int d = dst[e];
        int pos = atomicAdd(&cursor[d], 1);
        csr[pos] = src[e];
    }
}

// ---------------- dense GEMM: out[r][c] = (X[r][:] @ W[:, c]) * dinv[r] ----------------
// X: [N][128], W: [128][128], out: [N][128]. Tile: 64 rows x 128 cols, 512 threads.

__global__ __launch_bounds__(512) void gemm128(const float* __restrict__ X,
                                               const float* __restrict__ W,
                                               const float* __restrict__ dinv,
                                               float* __restrict__ out, int N) {
    __shared__ float xs[64][128];   // 32 KB
    __shared__ float ws[128][128];  // 64 KB
    int tid = threadIdx.x;
    int row0 = blockIdx.x * 64;

    // stage W (16384 floats = 4096 float4, 8 per thread)
    #pragma unroll
    for (int i = 0; i < 8; ++i)
        ((float4*)ws)[i * 512 + tid] = ((const float4*)W)[i * 512 + tid];

    // stage X tile (8192 floats = 2048 float4, 4 per thread)
    #pragma unroll
    for (int i = 0; i < 4; ++i) {
        int idx = i * 512 + tid;
        int r = idx >> 5, c = idx & 31;
        float4 v = make_float4(0.f, 0.f, 0.f, 0.f);
        if (row0 + r < N) v = *(const float4*)(X + (size_t)(row0 + r) * 128 + c * 4);
        *(float4*)&xs[r][c * 4] = v;
    }
    __syncthreads();

    int ty = tid >> 5;   // 0..15 -> rows ty*4..+3
    int tx = tid & 31;   // 0..31 -> cols tx*4..+3
    float acc[4][4] = {};
    #pragma unroll 4
    for (int k = 0; k < 128; ++k) {
        float4 wv = *(const float4*)&ws[k][tx * 4];
        #pragma unroll
        for (int i = 0; i < 4; ++i) {
            float xv = xs[ty * 4 + i][k];
            acc[i][0] = fmaf(xv, wv.x, acc[i][0]);
            acc[i][1] = fmaf(xv, wv.y, acc[i][1]);
            acc[i][2] = fmaf(xv, wv.z, acc[i][2]);
            acc[i][3] = fmaf(xv, wv.w, acc[i][3]);
        }
    }

    #pragma unroll
    for (int i = 0; i < 4; ++i) {
        int r = row0 + ty * 4 + i;
        if (r < N) {
            float dv = dinv[r];
            float4 o = make_float4(acc[i][0] * dv, acc[i][1] * dv,
                                   acc[i][2] * dv, acc[i][3] * dv);
            *(float4*)&out[(size_t)r * 128 + tx * 4] = o;
        }
    }
}

// layer 4: X [N][128] @ W4 [128][16] -> out [N][16], scaled by dinv
__global__ __launch_bounds__(256) void gemm16(const float* __restrict__ X,
                                              const float* __restrict__ W,
                                              const float* __restrict__ dinv,
                                              float* __restrict__ out, int N) {
    __shared__ float xs[64][128];  // 32 KB
    __shared__ float ws4[128][16]; // 8 KB
    int tid = threadIdx.x;
    int row0 = blockIdx.x * 64;

    #pragma unroll
    for (int i = 0; i < 2; ++i)
        ((float4*)ws4)[i * 256 + tid] = ((const float4*)W)[i * 256 + tid];

    #pragma unroll
    for (int i = 0; i < 8; ++i) {
        int idx = i * 256 + tid;
        int r = idx >> 5, c = idx & 31;
        float4 v = make_float4(0.f, 0.f, 0.f, 0.f);
        if (row0 + r < N) v = *(const float4*)(X + (size_t)(row0 + r) * 128 + c * 4);
        *(float4*)&xs[r][c * 4] = v;
    }
    __syncthreads();

    int ty = tid >> 4;  // 0..15 -> rows ty*4..+3
    int tx = tid & 15;  // col
    float acc[4] = {};
    #pragma unroll 4
    for (int k = 0; k < 128; ++k) {
        float wv = ws4[k][tx];
        #pragma unroll
        for (int i = 0; i < 4; ++i)
            acc[i] = fmaf(xs[ty * 4 + i][k], wv, acc[i]);
    }
    #pragma unroll
    for (int i = 0; i < 4; ++i) {
        int r = row0 + ty * 4 + i;
        if (r < N) out[(size_t)r * 16 + tx] = acc[i] * dinv[r];
    }
}

// ---------------- aggregation: one wave per node, 128 feats (float2/lane) ----------------
// out[n] = ACT( dinv[n] * (sum_{e in in(n)} HS[src[e]] + HS[n]) + b )
// ACT: 0 = identity, 1 = tanh, 2 = leaky_relu(0.01)

template <int ACT>
__global__ __launch_bounds__(256) void agg128(const float* __restrict__ HS,
                                              const int* __restrict__ rp,
                                              const int* __restrict__ csr,
                                              const float* __restrict__ dinv,
                                              const float* __restrict__ b,
                                              float* __restrict__ out, int N) {
    int wid = threadIdx.x >> 6, lane = threadIdx.x & 63;
    int n = blockIdx.x * 4 + wid;
    if (n >= N) return;
    const float2* H2 = (const float2*)HS;
    float2 acc = H2[(size_t)n * 64 + lane];  // self term
    int e = rp[n], end = rp[n + 1];
    for (; e < end; ++e) {
        int s = csr[e];
        float2 v = H2[(size_t)s * 64 + lane];
        acc.x += v.x;
        acc.y += v.y;
    }
    float dv = dinv[n];
    float2 bb = ((const float2*)b)[lane];
    float ox = fmaf(dv, acc.x, bb.x);
    float oy = fmaf(dv, acc.y, bb.y);
    if (ACT == 1) { ox = tanhf(ox); oy = tanhf(oy); }
    else if (ACT == 2) {
        ox = ox > 0.f ? ox : 0.01f * ox;
        oy = oy > 0.f ? oy : 0.01f * oy;
    }
    ((float2*)out)[(size_t)n * 64 + lane] = make_float2(ox, oy);
}

// ---------------- layer-4 aggregation + classifier head ----------------
// t = leaky( dinv[n]*(sum HS4[src] + HS4[n]) + b4 ); out[n] = elu(t . Wc + bc)

__global__ __launch_bounds__(256) void final_layer(const float* __restrict__ HS4,
                                                   const int* __restrict__ rp,
                                                   const int* __restrict__ csr,
                                                   const float* __restrict__ dinv,
                                                   const float* __restrict__ b4,
                                                   const float* __restrict__ Wc,
                                                   const float* __restrict__ bc,
                                                   float* __restrict__ out, int N) {
    int wid = threadIdx.x >> 6, lane = threadIdx.x & 63;
    int n = blockIdx.x * 4 + wid;
    if (n >= N) return;
    int f = lane & 15, g = lane >> 4;  // 4 edge-groups x 16 feats
    float acc = 0.f;
    int beg = rp[n], end = rp[n + 1];
    for (int e = beg + g; e < end; e += 4)
        acc += HS4[(size_t)csr[e] * 16 + f];
    acc += __shfl_xor(acc, 16);
    acc += __shfl_xor(acc, 32);
    acc += HS4[(size_t)n * 16 + f];  // self
    float t = fmaf(dinv[n], acc, b4[f]);
    t = t > 0.f ? t : 0.01f * t;
    float p = t * Wc[f];
    p += __shfl_xor(p, 1);
    p += __shfl_xor(p, 2);
    p += __shfl_xor(p, 4);
    p += __shfl_xor(p, 8);
    if (lane == 0) {
        float z = p + bc[0];
        out[n] = z > 0.f ? z : expm1f(z);
    }
}

// ---------------- launch ----------------

extern "C" void kernel_launch(void* const* d_in, const int* in_sizes, int n_in,
                              void* d_out, int out_size, void* d_ws, size_t ws_size,
                              hipStream_t stream) {
    const int N = NN, E = NE;
    const float* x  = (const float*)d_in[0];
    const int*   ei = (const int*)d_in[1];
    const float* W1 = (const float*)d_in[2];
    const float* b1 = (const float*)d_in[3];
    const float* W2 = (const float*)d_in[4];
    const float* b2 = (const float*)d_in[5];
    const float* W3 = (const float*)d_in[6];
    const float* b3 = (const float*)d_in[7];
    const float* W4 = (const float*)d_in[8];
    const float* b4 = (const float*)d_in[9];
    const float* Wc = (const float*)d_in[10];
    const float* bc = (const float*)d_in[11];
    float* out = (float*)d_out;
    const int* src = ei;
    const int* dst = ei + E;

    char* p = (char*)d_ws;
    auto carve = [&](size_t bytes) -> char* {
        char* q = p;
        p += (bytes + 255) & ~(size_t)255;
        return q;
    };
    int*   cnt    = (int*)carve((size_t)N * 4);
    int*   rowptr = (int*)carve((size_t)(N + 1) * 4);
    int*   cursor = (int*)carve((size_t)N * 4);
    float* dinv   = (float*)carve((size_t)N * 4);
    int*   csr    = (int*)carve((size_t)E * 4);
    float* bufA   = (float*)carve((size_t)N * 128 * 4);
    float* bufB   = (float*)carve((size_t)N * 128 * 4);

    // preprocessing: degree -> scan -> dinv -> CSR scatter
    zero_i32<<<(N + 255) / 256, 256, 0, stream>>>(cnt, N);
    count_deg<<<(E + 255) / 256, 256, 0, stream>>>(dst, cnt, E);
    scan_deg<<<1, 1024, 0, stream>>>(cnt, rowptr, cursor, N);
    calc_dinv<<<(N + 255) / 256, 256, 0, stream>>>(cnt, dinv, N);
    scatter_csr<<<(E + 255) / 256, 256, 0, stream>>>(src, dst, cursor, csr, E);

    int gblocks = (N + 63) / 64;
    int ablocks = (N + 3) / 4;

    // layer 1: h = x@W1 * dinv ; agg + b1 (identity)
    gemm128<<<gblocks, 512, 0, stream>>>(x, W1, dinv, bufB, N);
    agg128<0><<<ablocks, 256, 0, stream>>>(bufB, rowptr, csr, dinv, b1, bufA, N);
    // layer 2: tanh
    gemm128<<<gblocks, 512, 0, stream>>>(bufA, W2, dinv, bufB, N);
    agg128<1><<<ablocks, 256, 0, stream>>>(bufB, rowptr, csr, dinv, b2, bufA, N);
    // layer 3: leaky_relu
    gemm128<<<gblocks, 512, 0, stream>>>(bufA, W3, dinv, bufB, N);
    agg128<2><<<ablocks, 256, 0, stream>>>(bufB, rowptr, csr, dinv, b3, bufA, N);
    // layer 4 (128->16) + head
    gemm16<<<gblocks, 256, 0, stream>>>(bufA, W4, dinv, bufB, N);
    final_layer<<<ablocks, 256, 0, stream>>>(bufB, rowptr, csr, dinv, b4, Wc, bc, out, N);
}

// Round 2
// 424.999 us; speedup vs baseline: 1.4332x; 1.4332x over previous
//
#include <hip/hip_runtime.h>
#include <hip/hip_bf16.h>
#include <cstdint>
#include <cstddef>

#define NN 50000
#define NE 800000

// ---------------- preprocessing ----------------

__global__ __launch_bounds__(256) void zero_i32(int* __restrict__ p, int n) {
    int i = blockIdx.x * 256 + threadIdx.x;
    if (i < n) p[i] = 0;
}

__global__ __launch_bounds__(256) void count_deg(const int* __restrict__ dst,
                                                 int* __restrict__ cnt, int E) {
    int e = blockIdx.x * 256 + threadIdx.x;
    if (e < E) atomicAdd(&cnt[dst[e]], 1);
}

// scan stage 1: per-block (1024) exclusive scan via wave shuffles; also dinv
__global__ __launch_bounds__(1024) void scan1(const int* __restrict__ cnt,
                                              int* __restrict__ local,
                                              int* __restrict__ bsum,
                                              float* __restrict__ dinv, int N) {
    int t = threadIdx.x;
    int g = blockIdx.x * 1024 + t;
    int lane = t & 63, w = t >> 6;
    int v = (g < N) ? cnt[g] : 0;
    if (g < N) dinv[g] = rsqrtf((float)v + 1.0f);
    int x = v;
    #pragma unroll
    for (int off = 1; off < 64; off <<= 1) {
        int y = __shfl_up(x, off);
        if (lane >= off) x += y;
    }
    __shared__ int wsum[16];
    if (lane == 63) wsum[w] = x;
    __syncthreads();
    if (t < 16) {
        int s = wsum[t];
        int xx = s;
        #pragma unroll
        for (int off = 1; off < 16; off <<= 1) {
            int y = __shfl_up(xx, off);
            if (t >= off) xx += y;
        }
        wsum[t] = xx - s;  // exclusive wave offset
    }
    __syncthreads();
    int excl = wsum[w] + x - v;
    if (g < N) local[g] = excl;
    if (t == 1023) bsum[blockIdx.x] = excl + v;  // block total
}

// scan stage 2: single wave scans block sums (<=64 blocks) to exclusive
__global__ __launch_bounds__(64) void scan2(int* __restrict__ bsum, int NB) {
    int t = threadIdx.x;
    int v = (t < NB) ? bsum[t] : 0;
    int x = v;
    #pragma unroll
    for (int off = 1; off < 64; off <<= 1) {
        int y = __shfl_up(x, off);
        if (t >= off) x += y;
    }
    if (t < NB) bsum[t] = x - v;
}

// scan stage 3: add block offsets -> rowptr, cursor
__global__ __launch_bounds__(256) void scan3(const int* __restrict__ local,
                                             const int* __restrict__ bsum,
                                             int* __restrict__ rowptr,
                                             int* __restrict__ cursor, int N, int E) {
    int g = blockIdx.x * 256 + threadIdx.x;
    if (g < N) {
        int r = local[g] + bsum[g >> 10];
        rowptr[g] = r;
        cursor[g] = r;
    }
    if (g == 0) rowptr[N] = E;
}

__global__ __launch_bounds__(256) void scatter_csr(const int* __restrict__ src,
                                                   const int* __restrict__ dst,
                                                   int* __restrict__ cursor,
                                                   int* __restrict__ csr, int E) {
    int e = blockIdx.x * 256 + threadIdx.x;
    if (e < E) {
        int d = dst[e];
        int pos = atomicAdd(&cursor[d], 1);
        csr[pos] = src[e];
    }
}

// ---------------- dense GEMM: out[r][c] = (X[r][:] @ W[:, c]) * dinv[r] ----------------
// 64 rows x 128 cols per block, 512 threads, W staged in 32-k slices (48 KB LDS -> 3 blk/CU)

__global__ __launch_bounds__(512) void gemm128(const float* __restrict__ X,
                                               const float* __restrict__ W,
                                               const float* __restrict__ dinv,
                                               float* __restrict__ out, int N) {
    __shared__ float xs[64][128];   // 32 KB
    __shared__ float wss[32][128];  // 16 KB (k-slice)
    int tid = threadIdx.x;
    int row0 = blockIdx.x * 64;

    // stage X tile (8192 floats = 2048 float4, 4 per thread)
    #pragma unroll
    for (int i = 0; i < 4; ++i) {
        int idx = i * 512 + tid;
        int r = idx >> 5, c = idx & 31;
        float4 v = make_float4(0.f, 0.f, 0.f, 0.f);
        if (row0 + r < N) v = *(const float4*)(X + (size_t)(row0 + r) * 128 + c * 4);
        *(float4*)&xs[r][c * 4] = v;
    }

    int ty = tid >> 5;   // 0..15 -> rows ty*4..+3
    int tx = tid & 31;   // 0..31 -> cols tx*4..+3
    float acc[4][4] = {};

    for (int cchunk = 0; cchunk < 4; ++cchunk) {
        __syncthreads();  // protect wss from previous chunk's readers (and xs stage at c=0)
        // stage W k-slice [32][128]: 1024 float4, 2 per thread
        #pragma unroll
        for (int i = 0; i < 2; ++i)
            ((float4*)wss)[i * 512 + tid] = ((const float4*)W)[cchunk * 1024 + i * 512 + tid];
        __syncthreads();
        int kbase = cchunk * 32;
        #pragma unroll 8
        for (int k2 = 0; k2 < 32; ++k2) {
            float4 wv = *(const float4*)&wss[k2][tx * 4];
            #pragma unroll
            for (int i = 0; i < 4; ++i) {
                float xv = xs[ty * 4 + i][kbase + k2];
                acc[i][0] = fmaf(xv, wv.x, acc[i][0]);
                acc[i][1] = fmaf(xv, wv.y, acc[i][1]);
                acc[i][2] = fmaf(xv, wv.z, acc[i][2]);
                acc[i][3] = fmaf(xv, wv.w, acc[i][3]);
            }
        }
    }

    #pragma unroll
    for (int i = 0; i < 4; ++i) {
        int r = row0 + ty * 4 + i;
        if (r < N) {
            float dv = dinv[r];
            float4 o = make_float4(acc[i][0] * dv, acc[i][1] * dv,
                                   acc[i][2] * dv, acc[i][3] * dv);
            *(float4*)&out[(size_t)r * 128 + tx * 4] = o;
        }
    }
}

// layer 4: X [N][128] @ W4 [128][16] -> out [N][16], scaled by dinv
__global__ __launch_bounds__(256) void gemm16(const float* __restrict__ X,
                                              const float* __restrict__ W,
                                              const float* __restrict__ dinv,
                                              float* __restrict__ out, int N) {
    __shared__ float xs[64][128];  // 32 KB
    __shared__ float ws4[128][16]; // 8 KB
    int tid = threadIdx.x;
    int row0 = blockIdx.x * 64;

    #pragma unroll
    for (int i = 0; i < 2; ++i)
        ((float4*)ws4)[i * 256 + tid] = ((const float4*)W)[i * 256 + tid];

    #pragma unroll
    for (int i = 0; i < 8; ++i) {
        int idx = i * 256 + tid;
        int r = idx >> 5, c = idx & 31;
        float4 v = make_float4(0.f, 0.f, 0.f, 0.f);
        if (row0 + r < N) v = *(const float4*)(X + (size_t)(row0 + r) * 128 + c * 4);
        *(float4*)&xs[r][c * 4] = v;
    }
    __syncthreads();

    int ty = tid >> 4;  // 0..15 -> rows ty*4..+3
    int tx = tid & 15;  // col
    float acc[4] = {};
    #pragma unroll 4
    for (int k = 0; k < 128; ++k) {
        float wv = ws4[k][tx];
        #pragma unroll
        for (int i = 0; i < 4; ++i)
            acc[i] = fmaf(xs[ty * 4 + i][k], wv, acc[i]);
    }
    #pragma unroll
    for (int i = 0; i < 4; ++i) {
        int r = row0 + ty * 4 + i;
        if (r < N) out[(size_t)r * 16 + tx] = acc[i] * dinv[r];
    }
}

// ---------------- aggregation: one wave per node, unroll x4 for MLP ----------------
// out[n] = ACT( dinv[n] * (sum_{e in in(n)} HS[src[e]] + HS[n]) + b )

template <int ACT>
__global__ __launch_bounds__(256) void agg128(const float* __restrict__ HS,
                                              const int* __restrict__ rp,
                                              const int* __restrict__ csr,
                                              const float* __restrict__ dinv,
                                              const float* __restrict__ b,
                                              float* __restrict__ out, int N) {
    int wid = threadIdx.x >> 6, lane = threadIdx.x & 63;
    int n = blockIdx.x * 4 + wid;
    if (n >= N) return;
    const float2* H2 = (const float2*)HS;
    float2 a0 = H2[(size_t)n * 64 + lane];  // self term
    float2 a1 = make_float2(0.f, 0.f);
    float2 a2 = make_float2(0.f, 0.f);
    float2 a3 = make_float2(0.f, 0.f);
    int e = rp[n], end = rp[n + 1];
    for (; e + 4 <= end; e += 4) {
        int s0 = csr[e], s1 = csr[e + 1], s2 = csr[e + 2], s3 = csr[e + 3];
        float2 v0 = H2[(size_t)s0 * 64 + lane];
        float2 v1 = H2[(size_t)s1 * 64 + lane];
        float2 v2 = H2[(size_t)s2 * 64 + lane];
        float2 v3 = H2[(size_t)s3 * 64 + lane];
        a0.x += v0.x; a0.y += v0.y;
        a1.x += v1.x; a1.y += v1.y;
        a2.x += v2.x; a2.y += v2.y;
        a3.x += v3.x; a3.y += v3.y;
    }
    for (; e < end; ++e) {
        int s = csr[e];
        float2 v = H2[(size_t)s * 64 + lane];
        a0.x += v.x; a0.y += v.y;
    }
    float accx = (a0.x + a1.x) + (a2.x + a3.x);
    float accy = (a0.y + a1.y) + (a2.y + a3.y);
    float dv = dinv[n];
    float2 bb = ((const float2*)b)[lane];
    float ox = fmaf(dv, accx, bb.x);
    float oy = fmaf(dv, accy, bb.y);
    if (ACT == 1) { ox = tanhf(ox); oy = tanhf(oy); }
    else if (ACT == 2) {
        ox = ox > 0.f ? ox : 0.01f * ox;
        oy = oy > 0.f ? oy : 0.01f * oy;
    }
    ((float2*)out)[(size_t)n * 64 + lane] = make_float2(ox, oy);
}

// ---------------- layer-4 aggregation + classifier head ----------------

__global__ __launch_bounds__(256) void final_layer(const float* __restrict__ HS4,
                                                   const int* __restrict__ rp,
                                                   const int* __restrict__ csr,
                                                   const float* __restrict__ dinv,
                                                   const float* __restrict__ b4,
                                                   const float* __restrict__ Wc,
                                                   const float* __restrict__ bc,
                                                   float* __restrict__ out, int N) {
    int wid = threadIdx.x >> 6, lane = threadIdx.x & 63;
    int n = blockIdx.x * 4 + wid;
    if (n >= N) return;
    int f = lane & 15, g = lane >> 4;  // 4 edge-groups x 16 feats
    float acc = 0.f;
    int beg = rp[n], end = rp[n + 1];
    for (int e = beg + g; e < end; e += 4)
        acc += HS4[(size_t)csr[e] * 16 + f];
    acc += __shfl_xor(acc, 16);
    acc += __shfl_xor(acc, 32);
    acc += HS4[(size_t)n * 16 + f];  // self
    float t = fmaf(dinv[n], acc, b4[f]);
    t = t > 0.f ? t : 0.01f * t;
    float p = t * Wc[f];
    p += __shfl_xor(p, 1);
    p += __shfl_xor(p, 2);
    p += __shfl_xor(p, 4);
    p += __shfl_xor(p, 8);
    if (lane == 0) {
        float z = p + bc[0];
        out[n] = z > 0.f ? z : expm1f(z);
    }
}

// ---------------- launch ----------------

extern "C" void kernel_launch(void* const* d_in, const int* in_sizes, int n_in,
                              void* d_out, int out_size, void* d_ws, size_t ws_size,
                              hipStream_t stream) {
    const int N = NN, E = NE;
    const float* x  = (const float*)d_in[0];
    const int*   ei = (const int*)d_in[1];
    const float* W1 = (const float*)d_in[2];
    const float* b1 = (const float*)d_in[3];
    const float* W2 = (const float*)d_in[4];
    const float* b2 = (const float*)d_in[5];
    const float* W3 = (const float*)d_in[6];
    const float* b3 = (const float*)d_in[7];
    const float* W4 = (const float*)d_in[8];
    const float* b4 = (const float*)d_in[9];
    const float* Wc = (const float*)d_in[10];
    const float* bc = (const float*)d_in[11];
    float* out = (float*)d_out;
    const int* src = ei;
    const int* dst = ei + E;

    char* p = (char*)d_ws;
    auto carve = [&](size_t bytes) -> char* {
        char* q = p;
        p += (bytes + 255) & ~(size_t)255;
        return q;
    };
    int*   cnt    = (int*)carve((size_t)N * 4);
    int*   rowptr = (int*)carve((size_t)(N + 1) * 4);
    int*   cursor = (int*)carve((size_t)N * 4);
    float* dinv   = (float*)carve((size_t)N * 4);
    int*   csr    = (int*)carve((size_t)E * 4);
    int*   locsc  = (int*)carve((size_t)N * 4);
    int*   bsum   = (int*)carve((size_t)64 * 4);
    float* bufA   = (float*)carve((size_t)N * 128 * 4);
    float* bufB   = (float*)carve((size_t)N * 128 * 4);

    const int NB = (N + 1023) / 1024;  // 49

    // preprocessing: degree -> 3-stage scan (+dinv) -> CSR scatter
    zero_i32<<<(N + 255) / 256, 256, 0, stream>>>(cnt, N);
    count_deg<<<(E + 255) / 256, 256, 0, stream>>>(dst, cnt, E);
    scan1<<<NB, 1024, 0, stream>>>(cnt, locsc, bsum, dinv, N);
    scan2<<<1, 64, 0, stream>>>(bsum, NB);
    scan3<<<(N + 255) / 256, 256, 0, stream>>>(locsc, bsum, rowptr, cursor, N, E);
    scatter_csr<<<(E + 255) / 256, 256, 0, stream>>>(src, dst, cursor, csr, E);

    int gblocks = (N + 63) / 64;
    int ablocks = (N + 3) / 4;

    // layer 1: h = x@W1 * dinv ; agg + b1 (identity)
    gemm128<<<gblocks, 512, 0, stream>>>(x, W1, dinv, bufB, N);
    agg128<0><<<ablocks, 256, 0, stream>>>(bufB, rowptr, csr, dinv, b1, bufA, N);
    // layer 2: tanh
    gemm128<<<gblocks, 512, 0, stream>>>(bufA, W2, dinv, bufB, N);
    agg128<1><<<ablocks, 256, 0, stream>>>(bufB, rowptr, csr, dinv, b2, bufA, N);
    // layer 3: leaky_relu
    gemm128<<<gblocks, 512, 0, stream>>>(bufA, W3, dinv, bufB, N);
    agg128<2><<<ablocks, 256, 0, stream>>>(bufB, rowptr, csr, dinv, b3, bufA, N);
    // layer 4 (128->16) + head
    gemm16<<<gblocks, 256, 0, stream>>>(bufA, W4, dinv, bufB, N);
    final_layer<<<ablocks, 256, 0, stream>>>(bufB, rowptr, csr, dinv, b4, Wc, bc, out, N);
}

// Round 3
// 393.387 us; speedup vs baseline: 1.5483x; 1.0804x over previous
//
#include <hip/hip_runtime.h>
#include <hip/hip_bf16.h>
#include <cstdint>
#include <cstddef>

#define NN 50000
#define NE 800000

using short8v = __attribute__((ext_vector_type(8))) short;
using f32x4 = __attribute__((ext_vector_type(4))) float;

__device__ __forceinline__ unsigned short f2bf(float f) {
    unsigned u = __float_as_uint(f);
    u += 0x7fffu + ((u >> 16) & 1u);
    return (unsigned short)(u >> 16);
}
__device__ __forceinline__ float bf2f(unsigned s) {
    return __uint_as_float(s << 16);
}

// ---------------- preprocessing ----------------

__global__ __launch_bounds__(256) void zero_i32(int* __restrict__ p, int n) {
    int i = blockIdx.x * 256 + threadIdx.x;
    if (i < n) p[i] = 0;
}

__global__ __launch_bounds__(256) void count_deg(const int* __restrict__ dst,
                                                 int* __restrict__ cnt, int E) {
    int e = blockIdx.x * 256 + threadIdx.x;
    if (e < E) atomicAdd(&cnt[dst[e]], 1);
}

__global__ __launch_bounds__(1024) void scan1(const int* __restrict__ cnt,
                                              int* __restrict__ local,
                                              int* __restrict__ bsum,
                                              float* __restrict__ dinv, int N) {
    int t = threadIdx.x;
    int g = blockIdx.x * 1024 + t;
    int lane = t & 63, w = t >> 6;
    int v = (g < N) ? cnt[g] : 0;
    if (g < N) dinv[g] = rsqrtf((float)v + 1.0f);
    int x = v;
    #pragma unroll
    for (int off = 1; off < 64; off <<= 1) {
        int y = __shfl_up(x, off);
        if (lane >= off) x += y;
    }
    __shared__ int wsum[16];
    if (lane == 63) wsum[w] = x;
    __syncthreads();
    if (t < 16) {
        int s = wsum[t];
        int xx = s;
        #pragma unroll
        for (int off = 1; off < 16; off <<= 1) {
            int y = __shfl_up(xx, off);
            if (t >= off) xx += y;
        }
        wsum[t] = xx - s;
    }
    __syncthreads();
    int excl = wsum[w] + x - v;
    if (g < N) local[g] = excl;
    if (t == 1023) bsum[blockIdx.x] = excl + v;
}

__global__ __launch_bounds__(64) void scan2(int* __restrict__ bsum, int NB) {
    int t = threadIdx.x;
    int v = (t < NB) ? bsum[t] : 0;
    int x = v;
    #pragma unroll
    for (int off = 1; off < 64; off <<= 1) {
        int y = __shfl_up(x, off);
        if (t >= off) x += y;
    }
    if (t < NB) bsum[t] = x - v;
}

__global__ __launch_bounds__(256) void scan3(const int* __restrict__ local,
                                             const int* __restrict__ bsum,
                                             int* __restrict__ rowptr,
                                             int* __restrict__ cursor, int N, int E) {
    int g = blockIdx.x * 256 + threadIdx.x;
    if (g < N) {
        int r = local[g] + bsum[g >> 10];
        rowptr[g] = r;
        cursor[g] = r;
    }
    if (g == 0) rowptr[N] = E;
}

__global__ __launch_bounds__(256) void scatter_csr(const int* __restrict__ src,
                                                   const int* __restrict__ dst,
                                                   int* __restrict__ cursor,
                                                   int* __restrict__ csr, int E) {
    int e = blockIdx.x * 256 + threadIdx.x;
    if (e < E) {
        int d = dst[e];
        int pos = atomicAdd(&cursor[d], 1);
        csr[pos] = src[e];
    }
}

// ---------------- fp32 -> bf16 hi/lo split (layer-1 input) ----------------

__global__ __launch_bounds__(256) void cvt_split(const float* __restrict__ X,
                                                 unsigned* __restrict__ Xh,
                                                 unsigned* __restrict__ Xl,
                                                 int total4) {
    int i = blockIdx.x * 256 + threadIdx.x;
    int stride = gridDim.x * 256;
    for (; i < total4; i += stride) {
        float4 v = ((const float4*)X)[i];
        unsigned short h0 = f2bf(v.x), h1 = f2bf(v.y), h2 = f2bf(v.z), h3 = f2bf(v.w);
        float l0 = v.x - bf2f(h0), l1 = v.y - bf2f(h1);
        float l2 = v.z - bf2f(h2), l3 = v.w - bf2f(h3);
        uint2 hh = make_uint2((unsigned)h0 | ((unsigned)h1 << 16),
                              (unsigned)h2 | ((unsigned)h3 << 16));
        uint2 ll = make_uint2((unsigned)f2bf(l0) | ((unsigned)f2bf(l1) << 16),
                              (unsigned)f2bf(l2) | ((unsigned)f2bf(l3) << 16));
        ((uint2*)Xh)[i] = hh;
        ((uint2*)Xl)[i] = ll;
    }
}

// ---------------- bf16x3 MFMA GEMM: out = (X @ W) * dinv ----------------
// X given as bf16 hi/lo pair [N][128]; W fp32 [128][128]; out fp32 [N][128].
// Block: 64 rows, 256 thr (4 waves), wave tile 32x64. LDS 52KB -> 3 blk/CU.

__global__ __launch_bounds__(256) void gemm_mfma(const unsigned* __restrict__ Xh,
                                                 const unsigned* __restrict__ Xl,
                                                 const float* __restrict__ W,
                                                 const float* __restrict__ dinv,
                                                 float* __restrict__ out, int N) {
    __shared__ unsigned short xh[64 * 128];   // 16 KB, XOR-swizzled rows
    __shared__ unsigned short xl[64 * 128];   // 16 KB
    __shared__ unsigned short wh[128 * 40];   // 10 KB (W^T k-slice, rows padded to 40)
    __shared__ unsigned short wl[128 * 40];   // 10 KB
    int tid = threadIdx.x;
    int lane = tid & 63, wv = tid >> 6;
    int row0 = blockIdx.x * 64;

    // stage X tile: 1024 chunks of 8 bf16; swizzle elem-offset ^= (row&7)<<3
    #pragma unroll
    for (int i = 0; i < 4; ++i) {
        int id = i * 256 + tid;
        int r = id >> 4, kc = id & 15;
        uint4 vh = make_uint4(0, 0, 0, 0), vl = make_uint4(0, 0, 0, 0);
        if (row0 + r < N) {
            vh = *(const uint4*)&Xh[(size_t)(row0 + r) * 64 + kc * 4];
            vl = *(const uint4*)&Xl[(size_t)(row0 + r) * 64 + kc * 4];
        }
        int off = r * 128 + ((kc * 8) ^ ((r & 7) << 3));
        *(uint4*)&xh[off] = vh;
        *(uint4*)&xl[off] = vl;
    }

    int mstrip = (wv & 1) * 32;
    int nbase = (wv >> 1) * 64;
    f32x4 acc[2][4] = {};

    for (int ks = 0; ks < 4; ++ks) {
        __syncthreads();   // X ready (ks=0) / prior slice consumed
        // stage W^T slice: k in [ks*32, ks*32+32), packed as k-pairs into u32
        #pragma unroll
        for (int i = 0; i < 8; ++i) {
            int id = i * 256 + tid;          // 0..2047
            int kp = id >> 7, n = id & 127;
            int k0 = ks * 32 + kp * 2;
            float a = W[k0 * 128 + n];
            float b = W[(k0 + 1) * 128 + n];
            unsigned short ah = f2bf(a), bh = f2bf(b);
            float alo = a - bf2f(ah), blo = b - bf2f(bh);
            *(unsigned*)&wh[n * 40 + kp * 2] = (unsigned)ah | ((unsigned)bh << 16);
            *(unsigned*)&wl[n * 40 + kp * 2] =
                (unsigned)f2bf(alo) | ((unsigned)f2bf(blo) << 16);
        }
        __syncthreads();

        short8v afh[2], afl[2];
        #pragma unroll
        for (int mt = 0; mt < 2; ++mt) {
            int r = mstrip + mt * 16 + (lane & 15);
            int off = r * 128 + ((ks * 32 + ((lane >> 4) * 8)) ^ ((r & 7) << 3));
            afh[mt] = *(const short8v*)&xh[off];
            afl[mt] = *(const short8v*)&xl[off];
        }
        #pragma unroll
        for (int nt = 0; nt < 4; ++nt) {
            int c = nbase + nt * 16 + (lane & 15);
            int boff = c * 40 + (lane >> 4) * 8;
            short8v bfh = *(const short8v*)&wh[boff];
            short8v bfl = *(const short8v*)&wl[boff];
            #pragma unroll
            for (int mt = 0; mt < 2; ++mt) {
                acc[mt][nt] = __builtin_amdgcn_mfma_f32_16x16x32_bf16(afh[mt], bfh, acc[mt][nt], 0, 0, 0);
                acc[mt][nt] = __builtin_amdgcn_mfma_f32_16x16x32_bf16(afh[mt], bfl, acc[mt][nt], 0, 0, 0);
                acc[mt][nt] = __builtin_amdgcn_mfma_f32_16x16x32_bf16(afl[mt], bfh, acc[mt][nt], 0, 0, 0);
            }
        }
    }

    // epilogue: C/D layout col=lane&15, row=(lane>>4)*4+reg  [m89]
    #pragma unroll
    for (int mt = 0; mt < 2; ++mt) {
        #pragma unroll
        for (int i = 0; i < 4; ++i) {
            int r = row0 + mstrip + mt * 16 + (lane >> 4) * 4 + i;
            if (r < N) {
                float dv = dinv[r];
                #pragma unroll
                for (int nt = 0; nt < 4; ++nt) {
                    int cg = nbase + nt * 16 + (lane & 15);
                    out[(size_t)r * 128 + cg] = acc[mt][nt][i] * dv;
                }
            }
        }
    }
}

// layer 4: X (bf16 hi/lo) @ W4 [128][16] -> out [N][16] fp32, scaled by dinv
__global__ __launch_bounds__(256) void gemm16(const unsigned* __restrict__ Xh,
                                              const unsigned* __restrict__ Xl,
                                              const float* __restrict__ W,
                                              const float* __restrict__ dinv,
                                              float* __restrict__ out, int N) {
    __shared__ float xs[64][128];
    __shared__ float ws4[128][16];
    int tid = threadIdx.x;
    int row0 = blockIdx.x * 64;

    #pragma unroll
    for (int i = 0; i < 2; ++i)
        ((float4*)ws4)[i * 256 + tid] = ((const float4*)W)[i * 256 + tid];

    #pragma unroll
    for (int i = 0; i < 8; ++i) {
        int id = i * 256 + tid;
        int r = id >> 5, c4 = id & 31;
        float4 v = make_float4(0.f, 0.f, 0.f, 0.f);
        if (row0 + r < N) {
            uint2 hh = *(const uint2*)&Xh[(size_t)(row0 + r) * 64 + c4 * 2];
            uint2 ll = *(const uint2*)&Xl[(size_t)(row0 + r) * 64 + c4 * 2];
            v.x = bf2f(hh.x & 0xffffu) + bf2f(ll.x & 0xffffu);
            v.y = bf2f(hh.x >> 16) + bf2f(ll.x >> 16);
            v.z = bf2f(hh.y & 0xffffu) + bf2f(ll.y & 0xffffu);
            v.w = bf2f(hh.y >> 16) + bf2f(ll.y >> 16);
        }
        *(float4*)&xs[r][c4 * 4] = v;
    }
    __syncthreads();

    int ty = tid >> 4, tx = tid & 15;
    float acc[4] = {};
    #pragma unroll 4
    for (int k = 0; k < 128; ++k) {
        float wvv = ws4[k][tx];
        #pragma unroll
        for (int i = 0; i < 4; ++i)
            acc[i] = fmaf(xs[ty * 4 + i][k], wvv, acc[i]);
    }
    #pragma unroll
    for (int i = 0; i < 4; ++i) {
        int r = row0 + ty * 4 + i;
        if (r < N) out[(size_t)r * 16 + tx] = acc[i] * dinv[r];
    }
}

// ---------------- aggregation: one wave per node, unroll x8; emits bf16 hi/lo ----------------

template <int ACT>
__global__ __launch_bounds__(256) void agg128(const float* __restrict__ HS,
                                              const int* __restrict__ rp,
                                              const int* __restrict__ csr,
                                              const float* __restrict__ dinv,
                                              const float* __restrict__ b,
                                              unsigned* __restrict__ Xh,
                                              unsigned* __restrict__ Xl, int N) {
    int wid = threadIdx.x >> 6, lane = threadIdx.x & 63;
    int n = blockIdx.x * 4 + wid;
    if (n >= N) return;
    const float2* H2 = (const float2*)HS;
    float2 a0 = H2[(size_t)n * 64 + lane];  // self term
    float2 a1 = make_float2(0.f, 0.f), a2 = a1, a3 = a1;
    float2 a4 = a1, a5 = a1, a6 = a1, a7 = a1;
    int e = rp[n], end = rp[n + 1];
    for (; e + 8 <= end; e += 8) {
        int s0 = csr[e], s1 = csr[e + 1], s2 = csr[e + 2], s3 = csr[e + 3];
        int s4 = csr[e + 4], s5 = csr[e + 5], s6 = csr[e + 6], s7 = csr[e + 7];
        float2 v0 = H2[(size_t)s0 * 64 + lane];
        float2 v1 = H2[(size_t)s1 * 64 + lane];
        float2 v2 = H2[(size_t)s2 * 64 + lane];
        float2 v3 = H2[(size_t)s3 * 64 + lane];
        float2 v4 = H2[(size_t)s4 * 64 + lane];
        float2 v5 = H2[(size_t)s5 * 64 + lane];
        float2 v6 = H2[(size_t)s6 * 64 + lane];
        float2 v7 = H2[(size_t)s7 * 64 + lane];
        a0.x += v0.x; a0.y += v0.y; a1.x += v1.x; a1.y += v1.y;
        a2.x += v2.x; a2.y += v2.y; a3.x += v3.x; a3.y += v3.y;
        a4.x += v4.x; a4.y += v4.y; a5.x += v5.x; a5.y += v5.y;
        a6.x += v6.x; a6.y += v6.y; a7.x += v7.x; a7.y += v7.y;
    }
    if (e + 4 <= end) {
        int s0 = csr[e], s1 = csr[e + 1], s2 = csr[e + 2], s3 = csr[e + 3];
        float2 v0 = H2[(size_t)s0 * 64 + lane];
        float2 v1 = H2[(size_t)s1 * 64 + lane];
        float2 v2 = H2[(size_t)s2 * 64 + lane];
        float2 v3 = H2[(size_t)s3 * 64 + lane];
        a4.x += v0.x; a4.y += v0.y; a5.x += v1.x; a5.y += v1.y;
        a6.x += v2.x; a6.y += v2.y; a7.x += v3.x; a7.y += v3.y;
        e += 4;
    }
    for (; e < end; ++e) {
        int s = csr[e];
        float2 v = H2[(size_t)s * 64 + lane];
        a0.x += v.x; a0.y += v.y;
    }
    float accx = ((a0.x + a1.x) + (a2.x + a3.x)) + ((a4.x + a5.x) + (a6.x + a7.x));
    float accy = ((a0.y + a1.y) + (a2.y + a3.y)) + ((a4.y + a5.y) + (a6.y + a7.y));
    float dv = dinv[n];
    float2 bb = ((const float2*)b)[lane];
    float ox = fmaf(dv, accx, bb.x);
    float oy = fmaf(dv, accy, bb.y);
    if (ACT == 1) { ox = tanhf(ox); oy = tanhf(oy); }
    else if (ACT == 2) {
        ox = ox > 0.f ? ox : 0.01f * ox;
        oy = oy > 0.f ? oy : 0.01f * oy;
    }
    unsigned short h0 = f2bf(ox), h1 = f2bf(oy);
    float l0 = ox - bf2f(h0), l1 = oy - bf2f(h1);
    Xh[(size_t)n * 64 + lane] = (unsigned)h0 | ((unsigned)h1 << 16);
    Xl[(size_t)n * 64 + lane] = (unsigned)f2bf(l0) | ((unsigned)f2bf(l1) << 16);
}

// ---------------- layer-4 aggregation + classifier head ----------------

__global__ __launch_bounds__(256) void final_layer(const float* __restrict__ HS4,
                                                   const int* __restrict__ rp,
                                                   const int* __restrict__ csr,
                                                   const float* __restrict__ dinv,
                                                   const float* __restrict__ b4,
                                                   const float* __restrict__ Wc,
                                                   const float* __restrict__ bc,
                                                   float* __restrict__ out, int N) {
    int wid = threadIdx.x >> 6, lane = threadIdx.x & 63;
    int n = blockIdx.x * 4 + wid;
    if (n >= N) return;
    int f = lane & 15, g = lane >> 4;
    float acc = 0.f;
    int beg = rp[n], end = rp[n + 1];
    for (int e = beg + g; e < end; e += 4)
        acc += HS4[(size_t)csr[e] * 16 + f];
    acc += __shfl_xor(acc, 16);
    acc += __shfl_xor(acc, 32);
    acc += HS4[(size_t)n * 16 + f];
    float t = fmaf(dinv[n], acc, b4[f]);
    t = t > 0.f ? t : 0.01f * t;
    float p = t * Wc[f];
    p += __shfl_xor(p, 1);
    p += __shfl_xor(p, 2);
    p += __shfl_xor(p, 4);
    p += __shfl_xor(p, 8);
    if (lane == 0) {
        float z = p + bc[0];
        out[n] = z > 0.f ? z : expm1f(z);
    }
}

// ---------------- launch ----------------

extern "C" void kernel_launch(void* const* d_in, const int* in_sizes, int n_in,
                              void* d_out, int out_size, void* d_ws, size_t ws_size,
                              hipStream_t stream) {
    const int N = NN, E = NE;
    const float* x  = (const float*)d_in[0];
    const int*   ei = (const int*)d_in[1];
    const float* W1 = (const float*)d_in[2];
    const float* b1 = (const float*)d_in[3];
    const float* W2 = (const float*)d_in[4];
    const float* b2 = (const float*)d_in[5];
    const float* W3 = (const float*)d_in[6];
    const float* b3 = (const float*)d_in[7];
    const float* W4 = (const float*)d_in[8];
    const float* b4 = (const float*)d_in[9];
    const float* Wc = (const float*)d_in[10];
    const float* bc = (const float*)d_in[11];
    float* out = (float*)d_out;
    const int* src = ei;
    const int* dst = ei + E;

    char* p = (char*)d_ws;
    auto carve = [&](size_t bytes) -> char* {
        char* q = p;
        p += (bytes + 255) & ~(size_t)255;
        return q;
    };
    int*      cnt    = (int*)carve((size_t)N * 4);
    int*      rowptr = (int*)carve((size_t)(N + 1) * 4);
    int*      cursor = (int*)carve((size_t)N * 4);
    float*    dinv   = (float*)carve((size_t)N * 4);
    int*      csr    = (int*)carve((size_t)E * 4);
    int*      locsc  = (int*)carve((size_t)N * 4);
    int*      bsum   = (int*)carve((size_t)64 * 4);
    unsigned* Xh     = (unsigned*)carve((size_t)N * 64 * 4);
    unsigned* Xl     = (unsigned*)carve((size_t)N * 64 * 4);
    float*    bufB   = (float*)carve((size_t)N * 128 * 4);

    const int NB = (N + 1023) / 1024;

    zero_i32<<<(N + 255) / 256, 256, 0, stream>>>(cnt, N);
    count_deg<<<(E + 255) / 256, 256, 0, stream>>>(dst, cnt, E);
    scan1<<<NB, 1024, 0, stream>>>(cnt, locsc, bsum, dinv, N);
    scan2<<<1, 64, 0, stream>>>(bsum, NB);
    scan3<<<(N + 255) / 256, 256, 0, stream>>>(locsc, bsum, rowptr, cursor, N, E);
    scatter_csr<<<(E + 255) / 256, 256, 0, stream>>>(src, dst, cursor, csr, E);

    int gblocks = (N + 63) / 64;
    int ablocks = (N + 3) / 4;

    // layer-1 input split
    cvt_split<<<2048, 256, 0, stream>>>(x, Xh, Xl, N * 128 / 4);

    // layer 1
    gemm_mfma<<<gblocks, 256, 0, stream>>>(Xh, Xl, W1, dinv, bufB, N);
    agg128<0><<<ablocks, 256, 0, stream>>>(bufB, rowptr, csr, dinv, b1, Xh, Xl, N);
    // layer 2: tanh
    gemm_mfma<<<gblocks, 256, 0, stream>>>(Xh, Xl, W2, dinv, bufB, N);
    agg128<1><<<ablocks, 256, 0, stream>>>(bufB, rowptr, csr, dinv, b2, Xh, Xl, N);
    // layer 3: leaky_relu
    gemm_mfma<<<gblocks, 256, 0, stream>>>(Xh, Xl, W3, dinv, bufB, N);
    agg128<2><<<ablocks, 256, 0, stream>>>(bufB, rowptr, csr, dinv, b3, Xh, Xl, N);
    // layer 4 (128->16) + head
    gemm16<<<gblocks, 256, 0, stream>>>(Xh, Xl, W4, dinv, bufB, N);
    final_layer<<<ablocks, 256, 0, stream>>>(bufB, rowptr, csr, dinv, b4, Wc, bc, out, N);
}

// Round 4
// 357.111 us; speedup vs baseline: 1.7056x; 1.1016x over previous
//
#include <hip/hip_runtime.h>
#include <hip/hip_bf16.h>
#include <cstdint>
#include <cstddef>

#define NN 50000
#define NE 800000

using short8v = __attribute__((ext_vector_type(8))) short;
using f32x4 = __attribute__((ext_vector_type(4))) float;

__device__ __forceinline__ unsigned short f2bf(float f) {
    unsigned u = __float_as_uint(f);
    u += 0x7fffu + ((u >> 16) & 1u);
    return (unsigned short)(u >> 16);
}
__device__ __forceinline__ float bf2f(unsigned s) {
    return __uint_as_float(s << 16);
}

// ---------------- preprocessing ----------------

__global__ __launch_bounds__(256) void zero_i32(int* __restrict__ p, int n) {
    int i = blockIdx.x * 256 + threadIdx.x;
    if (i < n) p[i] = 0;
}

// padded counters (stride 17 ints = 68 B -> one counter per cache line);
// also records each edge's rank within its dst bucket (atomic-order invariant set).
__global__ __launch_bounds__(256) void count_deg_rank(const int* __restrict__ dst,
                                                      int* __restrict__ cntP,
                                                      int* __restrict__ rank, int E) {
    int e = blockIdx.x * 256 + threadIdx.x;
    if (e < E) {
        int d = dst[e];
        rank[e] = atomicAdd(&cntP[d * 17], 1);
    }
}

// scan stage 1: per-block (1024) exclusive scan via wave shuffles; also dinv
__global__ __launch_bounds__(1024) void scan1(const int* __restrict__ cntP,
                                              int* __restrict__ local,
                                              int* __restrict__ bsum,
                                              float* __restrict__ dinv, int N) {
    int t = threadIdx.x;
    int g = blockIdx.x * 1024 + t;
    int lane = t & 63, w = t >> 6;
    int v = (g < N) ? cntP[g * 17] : 0;
    if (g < N) dinv[g] = rsqrtf((float)v + 1.0f);
    int x = v;
    #pragma unroll
    for (int off = 1; off < 64; off <<= 1) {
        int y = __shfl_up(x, off);
        if (lane >= off) x += y;
    }
    __shared__ int wsum[16];
    if (lane == 63) wsum[w] = x;
    __syncthreads();
    if (t < 16) {
        int s = wsum[t];
        int xx = s;
        #pragma unroll
        for (int off = 1; off < 16; off <<= 1) {
            int y = __shfl_up(xx, off);
            if (t >= off) xx += y;
        }
        wsum[t] = xx - s;
    }
    __syncthreads();
    int excl = wsum[w] + x - v;
    if (g < N) local[g] = excl;
    if (t == 1023) bsum[blockIdx.x] = excl + v;
}

__global__ __launch_bounds__(64) void scan2(int* __restrict__ bsum, int NB) {
    int t = threadIdx.x;
    int v = (t < NB) ? bsum[t] : 0;
    int x = v;
    #pragma unroll
    for (int off = 1; off < 64; off <<= 1) {
        int y = __shfl_up(x, off);
        if (t >= off) x += y;
    }
    if (t < NB) bsum[t] = x - v;
}

__global__ __launch_bounds__(256) void scan3(const int* __restrict__ local,
                                             const int* __restrict__ bsum,
                                             int* __restrict__ rowptr, int N, int E) {
    int g = blockIdx.x * 256 + threadIdx.x;
    if (g < N) rowptr[g] = local[g] + bsum[g >> 10];
    if (g == 0) rowptr[N] = E;
}

// atomic-free scatter using precomputed ranks
__global__ __launch_bounds__(256) void scatter_plain(const int* __restrict__ src,
                                                     const int* __restrict__ dst,
                                                     const int* __restrict__ rowptr,
                                                     const int* __restrict__ rank,
                                                     int* __restrict__ csr, int E) {
    int e = blockIdx.x * 256 + threadIdx.x;
    if (e < E) {
        int d = dst[e];
        csr[rowptr[d] + rank[e]] = src[e];
    }
}

// ---------------- fp32 -> bf16 hi/lo split (layer-1 input) ----------------

__global__ __launch_bounds__(256) void cvt_split(const float* __restrict__ X,
                                                 unsigned* __restrict__ Xh,
                                                 unsigned* __restrict__ Xl,
                                                 int total4) {
    int i = blockIdx.x * 256 + threadIdx.x;
    int stride = gridDim.x * 256;
    for (; i < total4; i += stride) {
        float4 v = ((const float4*)X)[i];
        unsigned short h0 = f2bf(v.x), h1 = f2bf(v.y), h2 = f2bf(v.z), h3 = f2bf(v.w);
        float l0 = v.x - bf2f(h0), l1 = v.y - bf2f(h1);
        float l2 = v.z - bf2f(h2), l3 = v.w - bf2f(h3);
        uint2 hh = make_uint2((unsigned)h0 | ((unsigned)h1 << 16),
                              (unsigned)h2 | ((unsigned)h3 << 16));
        uint2 ll = make_uint2((unsigned)f2bf(l0) | ((unsigned)f2bf(l1) << 16),
                              (unsigned)f2bf(l2) | ((unsigned)f2bf(l3) << 16));
        ((uint2*)Xh)[i] = hh;
        ((uint2*)Xl)[i] = ll;
    }
}

// ---------------- bf16x3 MFMA GEMM: out = (X @ W) * dinv ----------------

__global__ __launch_bounds__(256) void gemm_mfma(const unsigned* __restrict__ Xh,
                                                 const unsigned* __restrict__ Xl,
                                                 const float* __restrict__ W,
                                                 const float* __restrict__ dinv,
                                                 float* __restrict__ out, int N) {
    __shared__ unsigned short xh[64 * 128];
    __shared__ unsigned short xl[64 * 128];
    __shared__ unsigned short wh[128 * 40];
    __shared__ unsigned short wl[128 * 40];
    int tid = threadIdx.x;
    int lane = tid & 63, wv = tid >> 6;
    int row0 = blockIdx.x * 64;

    #pragma unroll
    for (int i = 0; i < 4; ++i) {
        int id = i * 256 + tid;
        int r = id >> 4, kc = id & 15;
        uint4 vh = make_uint4(0, 0, 0, 0), vl = make_uint4(0, 0, 0, 0);
        if (row0 + r < N) {
            vh = *(const uint4*)&Xh[(size_t)(row0 + r) * 64 + kc * 4];
            vl = *(const uint4*)&Xl[(size_t)(row0 + r) * 64 + kc * 4];
        }
        int off = r * 128 + ((kc * 8) ^ ((r & 7) << 3));
        *(uint4*)&xh[off] = vh;
        *(uint4*)&xl[off] = vl;
    }

    int mstrip = (wv & 1) * 32;
    int nbase = (wv >> 1) * 64;
    f32x4 acc[2][4] = {};

    for (int ks = 0; ks < 4; ++ks) {
        __syncthreads();
        #pragma unroll
        for (int i = 0; i < 8; ++i) {
            int id = i * 256 + tid;
            int kp = id >> 7, n = id & 127;
            int k0 = ks * 32 + kp * 2;
            float a = W[k0 * 128 + n];
            float b = W[(k0 + 1) * 128 + n];
            unsigned short ah = f2bf(a), bh = f2bf(b);
            float alo = a - bf2f(ah), blo = b - bf2f(bh);
            *(unsigned*)&wh[n * 40 + kp * 2] = (unsigned)ah | ((unsigned)bh << 16);
            *(unsigned*)&wl[n * 40 + kp * 2] =
                (unsigned)f2bf(alo) | ((unsigned)f2bf(blo) << 16);
        }
        __syncthreads();

        short8v afh[2], afl[2];
        #pragma unroll
        for (int mt = 0; mt < 2; ++mt) {
            int r = mstrip + mt * 16 + (lane & 15);
            int off = r * 128 + ((ks * 32 + ((lane >> 4) * 8)) ^ ((r & 7) << 3));
            afh[mt] = *(const short8v*)&xh[off];
            afl[mt] = *(const short8v*)&xl[off];
        }
        #pragma unroll
        for (int nt = 0; nt < 4; ++nt) {
            int c = nbase + nt * 16 + (lane & 15);
            int boff = c * 40 + (lane >> 4) * 8;
            short8v bfh = *(const short8v*)&wh[boff];
            short8v bfl = *(const short8v*)&wl[boff];
            #pragma unroll
            for (int mt = 0; mt < 2; ++mt) {
                acc[mt][nt] = __builtin_amdgcn_mfma_f32_16x16x32_bf16(afh[mt], bfh, acc[mt][nt], 0, 0, 0);
                acc[mt][nt] = __builtin_amdgcn_mfma_f32_16x16x32_bf16(afh[mt], bfl, acc[mt][nt], 0, 0, 0);
                acc[mt][nt] = __builtin_amdgcn_mfma_f32_16x16x32_bf16(afl[mt], bfh, acc[mt][nt], 0, 0, 0);
            }
        }
    }

    #pragma unroll
    for (int mt = 0; mt < 2; ++mt) {
        #pragma unroll
        for (int i = 0; i < 4; ++i) {
            int r = row0 + mstrip + mt * 16 + (lane >> 4) * 4 + i;
            if (r < N) {
                float dv = dinv[r];
                #pragma unroll
                for (int nt = 0; nt < 4; ++nt) {
                    int cg = nbase + nt * 16 + (lane & 15);
                    out[(size_t)r * 128 + cg] = acc[mt][nt][i] * dv;
                }
            }
        }
    }
}

// layer 4: X (bf16 hi/lo) @ W4 [128][16] -> out [N][16] fp32, scaled by dinv
__global__ __launch_bounds__(256) void gemm16(const unsigned* __restrict__ Xh,
                                              const unsigned* __restrict__ Xl,
                                              const float* __restrict__ W,
                                              const float* __restrict__ dinv,
                                              float* __restrict__ out, int N) {
    __shared__ float xs[64][128];
    __shared__ float ws4[128][16];
    int tid = threadIdx.x;
    int row0 = blockIdx.x * 64;

    #pragma unroll
    for (int i = 0; i < 2; ++i)
        ((float4*)ws4)[i * 256 + tid] = ((const float4*)W)[i * 256 + tid];

    #pragma unroll
    for (int i = 0; i < 8; ++i) {
        int id = i * 256 + tid;
        int r = id >> 5, c4 = id & 31;
        float4 v = make_float4(0.f, 0.f, 0.f, 0.f);
        if (row0 + r < N) {
            uint2 hh = *(const uint2*)&Xh[(size_t)(row0 + r) * 64 + c4 * 2];
            uint2 ll = *(const uint2*)&Xl[(size_t)(row0 + r) * 64 + c4 * 2];
            v.x = bf2f(hh.x & 0xffffu) + bf2f(ll.x & 0xffffu);
            v.y = bf2f(hh.x >> 16) + bf2f(ll.x >> 16);
            v.z = bf2f(hh.y & 0xffffu) + bf2f(ll.y & 0xffffu);
            v.w = bf2f(hh.y >> 16) + bf2f(ll.y >> 16);
        }
        *(float4*)&xs[r][c4 * 4] = v;
    }
    __syncthreads();

    int ty = tid >> 4, tx = tid & 15;
    float acc[4] = {};
    #pragma unroll 4
    for (int k = 0; k < 128; ++k) {
        float wvv = ws4[k][tx];
        #pragma unroll
        for (int i = 0; i < 4; ++i)
            acc[i] = fmaf(xs[ty * 4 + i][k], wvv, acc[i]);
    }
    #pragma unroll
    for (int i = 0; i < 4; ++i) {
        int r = row0 + ty * 4 + i;
        if (r < N) out[(size_t)r * 16 + tx] = acc[i] * dinv[r];
    }
}

// ---------------- aggregation: one wave per node, 16 gathers in flight ----------------

template <int ACT>
__global__ __launch_bounds__(256) void agg128(const float* __restrict__ HS,
                                              const int* __restrict__ rp,
                                              const int* __restrict__ csr,
                                              const float* __restrict__ dinv,
                                              const float* __restrict__ b,
                                              unsigned* __restrict__ Xh,
                                              unsigned* __restrict__ Xl, int N) {
    int wid = threadIdx.x >> 6, lane = threadIdx.x & 63;
    int n = blockIdx.x * 4 + wid;
    if (n >= N) return;
    const float2* H2 = (const float2*)HS;
    float2 acc[8];
    acc[0] = H2[(size_t)n * 64 + lane];  // self term
    #pragma unroll
    for (int j = 1; j < 8; ++j) acc[j] = make_float2(0.f, 0.f);
    int e = rp[n], end = rp[n + 1];
    for (; e + 16 <= end; e += 16) {
        int s[16];
        #pragma unroll
        for (int j = 0; j < 16; ++j) s[j] = csr[e + j];
        float2 v[16];
        #pragma unroll
        for (int j = 0; j < 16; ++j) v[j] = H2[(size_t)s[j] * 64 + lane];
        #pragma unroll
        for (int j = 0; j < 8; ++j) {
            acc[j].x += v[j].x + v[j + 8].x;
            acc[j].y += v[j].y + v[j + 8].y;
        }
    }
    if (e + 8 <= end) {
        int s[8];
        #pragma unroll
        for (int j = 0; j < 8; ++j) s[j] = csr[e + j];
        float2 v[8];
        #pragma unroll
        for (int j = 0; j < 8; ++j) v[j] = H2[(size_t)s[j] * 64 + lane];
        #pragma unroll
        for (int j = 0; j < 8; ++j) {
            acc[j].x += v[j].x;
            acc[j].y += v[j].y;
        }
        e += 8;
    }
    if (e + 4 <= end) {
        int s[4];
        #pragma unroll
        for (int j = 0; j < 4; ++j) s[j] = csr[e + j];
        float2 v[4];
        #pragma unroll
        for (int j = 0; j < 4; ++j) v[j] = H2[(size_t)s[j] * 64 + lane];
        #pragma unroll
        for (int j = 0; j < 4; ++j) {
            acc[j + 4].x += v[j].x;
            acc[j + 4].y += v[j].y;
        }
        e += 4;
    }
    for (; e < end; ++e) {
        int s = csr[e];
        float2 v = H2[(size_t)s * 64 + lane];
        acc[0].x += v.x;
        acc[0].y += v.y;
    }
    float accx = ((acc[0].x + acc[1].x) + (acc[2].x + acc[3].x)) +
                 ((acc[4].x + acc[5].x) + (acc[6].x + acc[7].x));
    float accy = ((acc[0].y + acc[1].y) + (acc[2].y + acc[3].y)) +
                 ((acc[4].y + acc[5].y) + (acc[6].y + acc[7].y));
    float dv = dinv[n];
    float2 bb = ((const float2*)b)[lane];
    float ox = fmaf(dv, accx, bb.x);
    float oy = fmaf(dv, accy, bb.y);
    if (ACT == 1) { ox = tanhf(ox); oy = tanhf(oy); }
    else if (ACT == 2) {
        ox = ox > 0.f ? ox : 0.01f * ox;
        oy = oy > 0.f ? oy : 0.01f * oy;
    }
    unsigned short h0 = f2bf(ox), h1 = f2bf(oy);
    float l0 = ox - bf2f(h0), l1 = oy - bf2f(h1);
    Xh[(size_t)n * 64 + lane] = (unsigned)h0 | ((unsigned)h1 << 16);
    Xl[(size_t)n * 64 + lane] = (unsigned)f2bf(l0) | ((unsigned)f2bf(l1) << 16);
}

// ---------------- layer-4 aggregation + classifier head ----------------

__global__ __launch_bounds__(256) void final_layer(const float* __restrict__ HS4,
                                                   const int* __restrict__ rp,
                                                   const int* __restrict__ csr,
                                                   const float* __restrict__ dinv,
                                                   const float* __restrict__ b4,
                                                   const float* __restrict__ Wc,
                                                   const float* __restrict__ bc,
                                                   float* __restrict__ out, int N) {
    int wid = threadIdx.x >> 6, lane = threadIdx.x & 63;
    int n = blockIdx.x * 4 + wid;
    if (n >= N) return;
    int f = lane & 15, g = lane >> 4;
    float acc = 0.f;
    int beg = rp[n], end = rp[n + 1];
    for (int e = beg + g; e < end; e += 4)
        acc += HS4[(size_t)csr[e] * 16 + f];
    acc += __shfl_xor(acc, 16);
    acc += __shfl_xor(acc, 32);
    acc += HS4[(size_t)n * 16 + f];
    float t = fmaf(dinv[n], acc, b4[f]);
    t = t > 0.f ? t : 0.01f * t;
    float p = t * Wc[f];
    p += __shfl_xor(p, 1);
    p += __shfl_xor(p, 2);
    p += __shfl_xor(p, 4);
    p += __shfl_xor(p, 8);
    if (lane == 0) {
        float z = p + bc[0];
        out[n] = z > 0.f ? z : expm1f(z);
    }
}

// ---------------- launch ----------------

extern "C" void kernel_launch(void* const* d_in, const int* in_sizes, int n_in,
                              void* d_out, int out_size, void* d_ws, size_t ws_size,
                              hipStream_t stream) {
    const int N = NN, E = NE;
    const float* x  = (const float*)d_in[0];
    const int*   ei = (const int*)d_in[1];
    const float* W1 = (const float*)d_in[2];
    const float* b1 = (const float*)d_in[3];
    const float* W2 = (const float*)d_in[4];
    const float* b2 = (const float*)d_in[5];
    const float* W3 = (const float*)d_in[6];
    const float* b3 = (const float*)d_in[7];
    const float* W4 = (const float*)d_in[8];
    const float* b4 = (const float*)d_in[9];
    const float* Wc = (const float*)d_in[10];
    const float* bc = (const float*)d_in[11];
    float* out = (float*)d_out;
    const int* src = ei;
    const int* dst = ei + E;

    char* p = (char*)d_ws;
    auto carve = [&](size_t bytes) -> char* {
        char* q = p;
        p += (bytes + 255) & ~(size_t)255;
        return q;
    };
    int*      cntP   = (int*)carve((size_t)N * 17 * 4);
    int*      rank   = (int*)carve((size_t)E * 4);
    int*      rowptr = (int*)carve((size_t)(N + 1) * 4);
    float*    dinv   = (float*)carve((size_t)N * 4);
    int*      csr    = (int*)carve((size_t)E * 4);
    int*      locsc  = (int*)carve((size_t)N * 4);
    int*      bsum   = (int*)carve((size_t)64 * 4);
    unsigned* Xh     = (unsigned*)carve((size_t)N * 64 * 4);
    unsigned* Xl     = (unsigned*)carve((size_t)N * 64 * 4);
    float*    bufB   = (float*)carve((size_t)N * 128 * 4);

    const int NB = (N + 1023) / 1024;

    zero_i32<<<(N * 17 + 255) / 256, 256, 0, stream>>>(cntP, N * 17);
    count_deg_rank<<<(E + 255) / 256, 256, 0, stream>>>(dst, cntP, rank, E);
    scan1<<<NB, 1024, 0, stream>>>(cntP, locsc, bsum, dinv, N);
    scan2<<<1, 64, 0, stream>>>(bsum, NB);
    scan3<<<(N + 255) / 256, 256, 0, stream>>>(locsc, bsum, rowptr, N, E);
    scatter_plain<<<(E + 255) / 256, 256, 0, stream>>>(src, dst, rowptr, rank, csr, E);

    int gblocks = (N + 63) / 64;
    int ablocks = (N + 3) / 4;

    cvt_split<<<2048, 256, 0, stream>>>(x, Xh, Xl, N * 128 / 4);

    gemm_mfma<<<gblocks, 256, 0, stream>>>(Xh, Xl, W1, dinv, bufB, N);
    agg128<0><<<ablocks, 256, 0, stream>>>(bufB, rowptr, csr, dinv, b1, Xh, Xl, N);
    gemm_mfma<<<gblocks, 256, 0, stream>>>(Xh, Xl, W2, dinv, bufB, N);
    agg128<1><<<ablocks, 256, 0, stream>>>(bufB, rowptr, csr, dinv, b2, Xh, Xl, N);
    gemm_mfma<<<gblocks, 256, 0, stream>>>(Xh, Xl, W3, dinv, bufB, N);
    agg128<2><<<ablocks, 256, 0, stream>>>(bufB, rowptr, csr, dinv, b3, Xh, Xl, N);
    gemm16<<<gblocks, 256, 0, stream>>>(Xh, Xl, W4, dinv, bufB, N);
    final_layer<<<ablocks, 256, 0, stream>>>(bufB, rowptr, csr, dinv, b4, Wc, bc, out, N);
}

// Round 5
// 348.690 us; speedup vs baseline: 1.7468x; 1.0241x over previous
//
#include <hip/hip_runtime.h>
#include <hip/hip_bf16.h>
#include <cstdint>
#include <cstddef>

#define NN 50000
#define NE 800000

using short8v = __attribute__((ext_vector_type(8))) short;
using f32x4 = __attribute__((ext_vector_type(4))) float;

__device__ __forceinline__ unsigned short f2bf(float f) {
    unsigned u = __float_as_uint(f);
    u += 0x7fffu + ((u >> 16) & 1u);
    return (unsigned short)(u >> 16);
}
__device__ __forceinline__ float bf2f(unsigned s) {
    return __uint_as_float(s << 16);
}

// ---------------- preprocessing ----------------

__global__ __launch_bounds__(256) void zero_i32(int* __restrict__ p, int n) {
    int i = blockIdx.x * 256 + threadIdx.x;
    if (i < n) p[i] = 0;
}

// one counter per 64B line (stride 16 ints); also records edge rank in dst bucket
__global__ __launch_bounds__(256) void count_deg_rank(const int* __restrict__ dst,
                                                      int* __restrict__ cntP,
                                                      int* __restrict__ rank, int E) {
    int e = blockIdx.x * 256 + threadIdx.x;
    if (e < E) {
        int d = dst[e];
        rank[e] = atomicAdd(&cntP[d << 4], 1);
    }
}

__global__ __launch_bounds__(1024) void scan1(const int* __restrict__ cntP,
                                              int* __restrict__ local,
                                              int* __restrict__ bsum,
                                              float* __restrict__ dinv, int N) {
    int t = threadIdx.x;
    int g = blockIdx.x * 1024 + t;
    int lane = t & 63, w = t >> 6;
    int v = (g < N) ? cntP[g << 4] : 0;
    if (g < N) dinv[g] = rsqrtf((float)v + 1.0f);
    int x = v;
    #pragma unroll
    for (int off = 1; off < 64; off <<= 1) {
        int y = __shfl_up(x, off);
        if (lane >= off) x += y;
    }
    __shared__ int wsum[16];
    if (lane == 63) wsum[w] = x;
    __syncthreads();
    if (t < 16) {
        int s = wsum[t];
        int xx = s;
        #pragma unroll
        for (int off = 1; off < 16; off <<= 1) {
            int y = __shfl_up(xx, off);
            if (t >= off) xx += y;
        }
        wsum[t] = xx - s;
    }
    __syncthreads();
    int excl = wsum[w] + x - v;
    if (g < N) local[g] = excl;
    if (t == 1023) bsum[blockIdx.x] = excl + v;
}

__global__ __launch_bounds__(64) void scan2(int* __restrict__ bsum, int NB) {
    int t = threadIdx.x;
    int v = (t < NB) ? bsum[t] : 0;
    int x = v;
    #pragma unroll
    for (int off = 1; off < 64; off <<= 1) {
        int y = __shfl_up(x, off);
        if (t >= off) x += y;
    }
    if (t < NB) bsum[t] = x - v;
}

__global__ __launch_bounds__(256) void scan3(const int* __restrict__ local,
                                             const int* __restrict__ bsum,
                                             int* __restrict__ rowptr, int N, int E) {
    int g = blockIdx.x * 256 + threadIdx.x;
    if (g < N) rowptr[g] = local[g] + bsum[g >> 10];
    if (g == 0) rowptr[N] = E;
}

__global__ __launch_bounds__(256) void scatter_plain(const int* __restrict__ src,
                                                     const int* __restrict__ dst,
                                                     const int* __restrict__ rowptr,
                                                     const int* __restrict__ rank,
                                                     int* __restrict__ csr, int E) {
    int e = blockIdx.x * 256 + threadIdx.x;
    if (e < E) {
        int d = dst[e];
        csr[rowptr[d] + rank[e]] = src[e];
    }
}

// ---------------- W pre-split + transpose: W[k][n] fp32 -> WT{h,l}[n][k] bf16 ----------------
// gridDim.y selects which weight matrix (all 128x128).

__global__ __launch_bounds__(256) void split_wt(const float* __restrict__ Wa,
                                                const float* __restrict__ Wb,
                                                const float* __restrict__ Wc,
                                                unsigned short* __restrict__ WTh,
                                                unsigned short* __restrict__ WTl) {
    const float* W = (blockIdx.y == 0) ? Wa : (blockIdx.y == 1) ? Wb : Wc;
    int i = blockIdx.x * 256 + threadIdx.x;   // 0..16383, n-major
    int n = i >> 7, k = i & 127;
    float v = W[k * 128 + n];
    unsigned short h = f2bf(v);
    float lo = v - bf2f(h);
    size_t base = (size_t)blockIdx.y * 16384 + i;
    WTh[base] = h;
    WTl[base] = f2bf(lo);
}

// ---------------- bf16x3 MFMA GEMM: out = (X @ W) * dinv ----------------
// X: fp32 [N][128] (F32IN) or bf16 hi/lo pair (else). WT: pre-split [n][k] bf16.
// Block: 64 rows, 256 thr (4 waves), wave tile 32x64. LDS 32KB. One sync.

template <bool F32IN>
__global__ __launch_bounds__(256) void gemm_mfma(const void* __restrict__ Xin,
                                                 const void* __restrict__ Xlin,
                                                 const unsigned short* __restrict__ WTh,
                                                 const unsigned short* __restrict__ WTl,
                                                 const float* __restrict__ dinv,
                                                 float* __restrict__ out, int N) {
    __shared__ unsigned short xh[64 * 128];   // 16 KB, XOR-swizzled
    __shared__ unsigned short xl[64 * 128];   // 16 KB
    int tid = threadIdx.x;
    int lane = tid & 63, wv = tid >> 6;
    int row0 = blockIdx.x * 64;

    #pragma unroll
    for (int i = 0; i < 4; ++i) {
        int id = i * 256 + tid;
        int r = id >> 4, kc = id & 15;   // kc: 8-elem chunk
        uint4 vh = make_uint4(0, 0, 0, 0), vl = make_uint4(0, 0, 0, 0);
        if (row0 + r < N) {
            if constexpr (F32IN) {
                const float* Xf = (const float*)Xin;
                float4 a = *(const float4*)(Xf + (size_t)(row0 + r) * 128 + kc * 8);
                float4 b = *(const float4*)(Xf + (size_t)(row0 + r) * 128 + kc * 8 + 4);
                unsigned short h0 = f2bf(a.x), h1 = f2bf(a.y), h2 = f2bf(a.z), h3 = f2bf(a.w);
                unsigned short h4 = f2bf(b.x), h5 = f2bf(b.y), h6 = f2bf(b.z), h7 = f2bf(b.w);
                vh = make_uint4((unsigned)h0 | ((unsigned)h1 << 16),
                                (unsigned)h2 | ((unsigned)h3 << 16),
                                (unsigned)h4 | ((unsigned)h5 << 16),
                                (unsigned)h6 | ((unsigned)h7 << 16));
                vl = make_uint4((unsigned)f2bf(a.x - bf2f(h0)) | ((unsigned)f2bf(a.y - bf2f(h1)) << 16),
                                (unsigned)f2bf(a.z - bf2f(h2)) | ((unsigned)f2bf(a.w - bf2f(h3)) << 16),
                                (unsigned)f2bf(b.x - bf2f(h4)) | ((unsigned)f2bf(b.y - bf2f(h5)) << 16),
                                (unsigned)f2bf(b.z - bf2f(h6)) | ((unsigned)f2bf(b.w - bf2f(h7)) << 16));
            } else {
                vh = *(const uint4*)&((const unsigned*)Xin)[(size_t)(row0 + r) * 64 + kc * 4];
                vl = *(const uint4*)&((const unsigned*)Xlin)[(size_t)(row0 + r) * 64 + kc * 4];
            }
        }
        int off = r * 128 + ((kc * 8) ^ ((r & 7) << 3));
        *(uint4*)&xh[off] = vh;
        *(uint4*)&xl[off] = vl;
    }
    __syncthreads();

    int mstrip = (wv & 1) * 32;
    int nbase = (wv >> 1) * 64;
    f32x4 acc[2][4] = {};

    #pragma unroll
    for (int ks = 0; ks < 4; ++ks) {
        short8v afh[2], afl[2];
        #pragma unroll
        for (int mt = 0; mt < 2; ++mt) {
            int r = mstrip + mt * 16 + (lane & 15);
            int off = r * 128 + ((ks * 32 + ((lane >> 4) * 8)) ^ ((r & 7) << 3));
            afh[mt] = *(const short8v*)&xh[off];
            afl[mt] = *(const short8v*)&xl[off];
        }
        #pragma unroll
        for (int nt = 0; nt < 4; ++nt) {
            int c = nbase + nt * 16 + (lane & 15);
            size_t goff = (size_t)c * 128 + ks * 32 + (lane >> 4) * 8;
            short8v bfh = *(const short8v*)&WTh[goff];
            short8v bfl = *(const short8v*)&WTl[goff];
            #pragma unroll
            for (int mt = 0; mt < 2; ++mt) {
                acc[mt][nt] = __builtin_amdgcn_mfma_f32_16x16x32_bf16(afh[mt], bfh, acc[mt][nt], 0, 0, 0);
                acc[mt][nt] = __builtin_amdgcn_mfma_f32_16x16x32_bf16(afh[mt], bfl, acc[mt][nt], 0, 0, 0);
                acc[mt][nt] = __builtin_amdgcn_mfma_f32_16x16x32_bf16(afl[mt], bfh, acc[mt][nt], 0, 0, 0);
            }
        }
    }

    // C/D layout: col=lane&15, row=(lane>>4)*4+reg  [m89]
    #pragma unroll
    for (int mt = 0; mt < 2; ++mt) {
        #pragma unroll
        for (int i = 0; i < 4; ++i) {
            int r = row0 + mstrip + mt * 16 + (lane >> 4) * 4 + i;
            if (r < N) {
                float dv = dinv[r];
                #pragma unroll
                for (int nt = 0; nt < 4; ++nt) {
                    int cg = nbase + nt * 16 + (lane & 15);
                    out[(size_t)r * 128 + cg] = acc[mt][nt][i] * dv;
                }
            }
        }
    }
}

// layer 4: X (bf16 hi/lo) @ W4 [128][16] -> out [N][16] fp32, scaled by dinv
__global__ __launch_bounds__(256) void gemm16(const unsigned* __restrict__ Xh,
                                              const unsigned* __restrict__ Xl,
                                              const float* __restrict__ W,
                                              const float* __restrict__ dinv,
                                              float* __restrict__ out, int N) {
    __shared__ float xs[64][128];
    __shared__ float ws4[128][16];
    int tid = threadIdx.x;
    int row0 = blockIdx.x * 64;

    #pragma unroll
    for (int i = 0; i < 2; ++i)
        ((float4*)ws4)[i * 256 + tid] = ((const float4*)W)[i * 256 + tid];

    #pragma unroll
    for (int i = 0; i < 8; ++i) {
        int id = i * 256 + tid;
        int r = id >> 5, c4 = id & 31;
        float4 v = make_float4(0.f, 0.f, 0.f, 0.f);
        if (row0 + r < N) {
            uint2 hh = *(const uint2*)&Xh[(size_t)(row0 + r) * 64 + c4 * 2];
            uint2 ll = *(const uint2*)&Xl[(size_t)(row0 + r) * 64 + c4 * 2];
            v.x = bf2f(hh.x & 0xffffu) + bf2f(ll.x & 0xffffu);
            v.y = bf2f(hh.x >> 16) + bf2f(ll.x >> 16);
            v.z = bf2f(hh.y & 0xffffu) + bf2f(ll.y & 0xffffu);
            v.w = bf2f(hh.y >> 16) + bf2f(ll.y >> 16);
        }
        *(float4*)&xs[r][c4 * 4] = v;
    }
    __syncthreads();

    int ty = tid >> 4, tx = tid & 15;
    float acc[4] = {};
    #pragma unroll 4
    for (int k = 0; k < 128; ++k) {
        float wvv = ws4[k][tx];
        #pragma unroll
        for (int i = 0; i < 4; ++i)
            acc[i] = fmaf(xs[ty * 4 + i][k], wvv, acc[i]);
    }
    #pragma unroll
    for (int i = 0; i < 4; ++i) {
        int r = row0 + ty * 4 + i;
        if (r < N) out[(size_t)r * 16 + tx] = acc[i] * dinv[r];
    }
}

// ---------------- aggregation: one wave per node, 8 gathers in flight ----------------

template <int ACT>
__global__ __launch_bounds__(256) void agg128(const float* __restrict__ HS,
                                              const int* __restrict__ rp,
                                              const int* __restrict__ csr,
                                              const float* __restrict__ dinv,
                                              const float* __restrict__ b,
                                              unsigned* __restrict__ Xh,
                                              unsigned* __restrict__ Xl, int N) {
    int wid = threadIdx.x >> 6, lane = threadIdx.x & 63;
    int n = blockIdx.x * 4 + wid;
    if (n >= N) return;
    const float2* H2 = (const float2*)HS;
    float2 a0 = H2[(size_t)n * 64 + lane];  // self term
    float2 a1 = make_float2(0.f, 0.f), a2 = a1, a3 = a1;
    float2 a4 = a1, a5 = a1, a6 = a1, a7 = a1;
    int e = rp[n], end = rp[n + 1];
    for (; e + 8 <= end; e += 8) {
        int s0 = csr[e], s1 = csr[e + 1], s2 = csr[e + 2], s3 = csr[e + 3];
        int s4 = csr[e + 4], s5 = csr[e + 5], s6 = csr[e + 6], s7 = csr[e + 7];
        float2 v0 = H2[(size_t)s0 * 64 + lane];
        float2 v1 = H2[(size_t)s1 * 64 + lane];
        float2 v2 = H2[(size_t)s2 * 64 + lane];
        float2 v3 = H2[(size_t)s3 * 64 + lane];
        float2 v4 = H2[(size_t)s4 * 64 + lane];
        float2 v5 = H2[(size_t)s5 * 64 + lane];
        float2 v6 = H2[(size_t)s6 * 64 + lane];
        float2 v7 = H2[(size_t)s7 * 64 + lane];
        a0.x += v0.x; a0.y += v0.y; a1.x += v1.x; a1.y += v1.y;
        a2.x += v2.x; a2.y += v2.y; a3.x += v3.x; a3.y += v3.y;
        a4.x += v4.x; a4.y += v4.y; a5.x += v5.x; a5.y += v5.y;
        a6.x += v6.x; a6.y += v6.y; a7.x += v7.x; a7.y += v7.y;
    }
    if (e + 4 <= end) {
        int s0 = csr[e], s1 = csr[e + 1], s2 = csr[e + 2], s3 = csr[e + 3];
        float2 v0 = H2[(size_t)s0 * 64 + lane];
        float2 v1 = H2[(size_t)s1 * 64 + lane];
        float2 v2 = H2[(size_t)s2 * 64 + lane];
        float2 v3 = H2[(size_t)s3 * 64 + lane];
        a4.x += v0.x; a4.y += v0.y; a5.x += v1.x; a5.y += v1.y;
        a6.x += v2.x; a6.y += v2.y; a7.x += v3.x; a7.y += v3.y;
        e += 4;
    }
    for (; e < end; ++e) {
        int s = csr[e];
        float2 v = H2[(size_t)s * 64 + lane];
        a0.x += v.x; a0.y += v.y;
    }
    float accx = ((a0.x + a1.x) + (a2.x + a3.x)) + ((a4.x + a5.x) + (a6.x + a7.x));
    float accy = ((a0.y + a1.y) + (a2.y + a3.y)) + ((a4.y + a5.y) + (a6.y + a7.y));
    float dv = dinv[n];
    float2 bb = ((const float2*)b)[lane];
    float ox = fmaf(dv, accx, bb.x);
    float oy = fmaf(dv, accy, bb.y);
    if (ACT == 1) { ox = tanhf(ox); oy = tanhf(oy); }
    else if (ACT == 2) {
        ox = ox > 0.f ? ox : 0.01f * ox;
        oy = oy > 0.f ? oy : 0.01f * oy;
    }
    unsigned short h0 = f2bf(ox), h1 = f2bf(oy);
    float l0 = ox - bf2f(h0), l1 = oy - bf2f(h1);
    Xh[(size_t)n * 64 + lane] = (unsigned)h0 | ((unsigned)h1 << 16);
    Xl[(size_t)n * 64 + lane] = (unsigned)f2bf(l0) | ((unsigned)f2bf(l1) << 16);
}

// ---------------- layer-4 aggregation + classifier head ----------------

__global__ __launch_bounds__(256) void final_layer(const float* __restrict__ HS4,
                                                   const int* __restrict__ rp,
                                                   const int* __restrict__ csr,
                                                   const float* __restrict__ dinv,
                                                   const float* __restrict__ b4,
                                                   const float* __restrict__ Wc,
                                                   const float* __restrict__ bc,
                                                   float* __restrict__ out, int N) {
    int wid = threadIdx.x >> 6, lane = threadIdx.x & 63;
    int n = blockIdx.x * 4 + wid;
    if (n >= N) return;
    int f = lane & 15, g = lane >> 4;
    float acc = 0.f;
    int beg = rp[n], end = rp[n + 1];
    for (int e = beg + g; e < end; e += 4)
        acc += HS4[(size_t)csr[e] * 16 + f];
    acc += __shfl_xor(acc, 16);
    acc += __shfl_xor(acc, 32);
    acc += HS4[(size_t)n * 16 + f];
    float t = fmaf(dinv[n], acc, b4[f]);
    t = t > 0.f ? t : 0.01f * t;
    float p = t * Wc[f];
    p += __shfl_xor(p, 1);
    p += __shfl_xor(p, 2);
    p += __shfl_xor(p, 4);
    p += __shfl_xor(p, 8);
    if (lane == 0) {
        float z = p + bc[0];
        out[n] = z > 0.f ? z : expm1f(z);
    }
}

// ---------------- launch ----------------

extern "C" void kernel_launch(void* const* d_in, const int* in_sizes, int n_in,
                              void* d_out, int out_size, void* d_ws, size_t ws_size,
                              hipStream_t stream) {
    const int N = NN, E = NE;
    const float* x  = (const float*)d_in[0];
    const int*   ei = (const int*)d_in[1];
    const float* W1 = (const float*)d_in[2];
    const float* b1 = (const float*)d_in[3];
    const float* W2 = (const float*)d_in[4];
    const float* b2 = (const float*)d_in[5];
    const float* W3 = (const float*)d_in[6];
    const float* b3 = (const float*)d_in[7];
    const float* W4 = (const float*)d_in[8];
    const float* b4 = (const float*)d_in[9];
    const float* Wc = (const float*)d_in[10];
    const float* bc = (const float*)d_in[11];
    float* out = (float*)d_out;
    const int* src = ei;
    const int* dst = ei + E;

    char* p = (char*)d_ws;
    auto carve = [&](size_t bytes) -> char* {
        char* q = p;
        p += (bytes + 255) & ~(size_t)255;
        return q;
    };
    int*            cntP   = (int*)carve((size_t)N * 16 * 4);
    int*            rank   = (int*)carve((size_t)E * 4);
    int*            rowptr = (int*)carve((size_t)(N + 1) * 4);
    float*          dinv   = (float*)carve((size_t)N * 4);
    int*            csr    = (int*)carve((size_t)E * 4);
    int*            locsc  = (int*)carve((size_t)N * 4);
    int*            bsum   = (int*)carve((size_t)64 * 4);
    unsigned short* WTh    = (unsigned short*)carve((size_t)3 * 16384 * 2);
    unsigned short* WTl    = (unsigned short*)carve((size_t)3 * 16384 * 2);
    unsigned*       Xh     = (unsigned*)carve((size_t)N * 64 * 4);
    unsigned*       Xl     = (unsigned*)carve((size_t)N * 64 * 4);
    float*          bufB   = (float*)carve((size_t)N * 128 * 4);

    const int NB = (N + 1023) / 1024;

    zero_i32<<<(N * 16 + 255) / 256, 256, 0, stream>>>(cntP, N * 16);
    count_deg_rank<<<(E + 255) / 256, 256, 0, stream>>>(dst, cntP, rank, E);
    scan1<<<NB, 1024, 0, stream>>>(cntP, locsc, bsum, dinv, N);
    scan2<<<1, 64, 0, stream>>>(bsum, NB);
    scan3<<<(N + 255) / 256, 256, 0, stream>>>(locsc, bsum, rowptr, N, E);
    scatter_plain<<<(E + 255) / 256, 256, 0, stream>>>(src, dst, rowptr, rank, csr, E);
    split_wt<<<dim3(64, 3), 256, 0, stream>>>(W1, W2, W3, WTh, WTl);

    int gblocks = (N + 63) / 64;
    int ablocks = (N + 3) / 4;

    gemm_mfma<true><<<gblocks, 256, 0, stream>>>(x, nullptr, WTh, WTl, dinv, bufB, N);
    agg128<0><<<ablocks, 256, 0, stream>>>(bufB, rowptr, csr, dinv, b1, Xh, Xl, N);
    gemm_mfma<false><<<gblocks, 256, 0, stream>>>(Xh, Xl, WTh + 16384, WTl + 16384, dinv, bufB, N);
    agg128<1><<<ablocks, 256, 0, stream>>>(bufB, rowptr, csr, dinv, b2, Xh, Xl, N);
    gemm_mfma<false><<<gblocks, 256, 0, stream>>>(Xh, Xl, WTh + 32768, WTl + 32768, dinv, bufB, N);
    agg128<2><<<ablocks, 256, 0, stream>>>(bufB, rowptr, csr, dinv, b3, Xh, Xl, N);
    gemm16<<<gblocks, 256, 0, stream>>>(Xh, Xl, W4, dinv, bufB, N);
    final_layer<<<ablocks, 256, 0, stream>>>(bufB, rowptr, csr, dinv, b4, Wc, bc, out, N);
}

// Round 6
// 330.826 us; speedup vs baseline: 1.8411x; 1.0540x over previous
//
#include <hip/hip_runtime.h>
#include <hip/hip_bf16.h>
#include <cstdint>
#include <cstddef>

#define NN 50000
#define NE 800000

using short8v = __attribute__((ext_vector_type(8))) short;
using f32x4 = __attribute__((ext_vector_type(4))) float;

__device__ __forceinline__ unsigned short f2bf(float f) {
    unsigned u = __float_as_uint(f);
    u += 0x7fffu + ((u >> 16) & 1u);
    return (unsigned short)(u >> 16);
}
__device__ __forceinline__ float bf2f(unsigned s) {
    return __uint_as_float(s << 16);
}

// ---------------- preprocessing ----------------

// one counter per 64B line (stride 16 ints); records edge rank in dst bucket
__global__ __launch_bounds__(256) void count_deg_rank(const int* __restrict__ dst,
                                                      int* __restrict__ cntP,
                                                      int* __restrict__ rank, int E) {
    int e = blockIdx.x * 256 + threadIdx.x;
    if (e < E) {
        int d = dst[e];
        rank[e] = atomicAdd(&cntP[d << 4], 1);
    }
}

__global__ __launch_bounds__(1024) void scan1(const int* __restrict__ cntP,
                                              int* __restrict__ local,
                                              int* __restrict__ bsum,
                                              float* __restrict__ dinv, int N) {
    int t = threadIdx.x;
    int g = blockIdx.x * 1024 + t;
    int lane = t & 63, w = t >> 6;
    int v = (g < N) ? cntP[g << 4] : 0;
    if (g < N) dinv[g] = rsqrtf((float)v + 1.0f);
    int x = v;
    #pragma unroll
    for (int off = 1; off < 64; off <<= 1) {
        int y = __shfl_up(x, off);
        if (lane >= off) x += y;
    }
    __shared__ int wsum[16];
    if (lane == 63) wsum[w] = x;
    __syncthreads();
    if (t < 16) {
        int s = wsum[t];
        int xx = s;
        #pragma unroll
        for (int off = 1; off < 16; off <<= 1) {
            int y = __shfl_up(xx, off);
            if (t >= off) xx += y;
        }
        wsum[t] = xx - s;
    }
    __syncthreads();
    int excl = wsum[w] + x - v;
    if (g < N) local[g] = excl;
    if (t == 1023) bsum[blockIdx.x] = excl + v;
}

// merged scan2+scan3: each block wave-scans the <=64 block sums in-register
__global__ __launch_bounds__(256) void scan3(const int* __restrict__ local,
                                             const int* __restrict__ bsum,
                                             int* __restrict__ rowptr,
                                             int N, int E, int NB) {
    __shared__ int sb[64];
    int t = threadIdx.x;
    if (t < 64) {
        int v = (t < NB) ? bsum[t] : 0;
        int x = v;
        #pragma unroll
        for (int off = 1; off < 64; off <<= 1) {
            int y = __shfl_up(x, off);
            if (t >= off) x += y;
        }
        sb[t] = x - v;
    }
    __syncthreads();
    int g = blockIdx.x * 256 + t;
    if (g < N) rowptr[g] = local[g] + sb[g >> 10];
    if (g == 0) rowptr[N] = E;
}

// scatter (atomic-free via rank) + tail blocks pre-split W1..W3 -> WT{h,l}[n][k] bf16
__global__ __launch_bounds__(256) void scatter_split(const int* __restrict__ src,
                                                     const int* __restrict__ dst,
                                                     const int* __restrict__ rowptr,
                                                     const int* __restrict__ rank,
                                                     int* __restrict__ csr, int E,
                                                     int sblocks,
                                                     const float* __restrict__ Wa,
                                                     const float* __restrict__ Wb,
                                                     const float* __restrict__ Wc,
                                                     unsigned short* __restrict__ WTh,
                                                     unsigned short* __restrict__ WTl) {
    if ((int)blockIdx.x < sblocks) {
        int e = blockIdx.x * 256 + threadIdx.x;
        if (e < E) {
            int d = dst[e];
            csr[rowptr[d] + rank[e]] = src[e];
        }
    } else {
        int i = (blockIdx.x - sblocks) * 256 + threadIdx.x;  // 0..49151
        int j = i >> 14;          // which W
        int idx = i & 16383;
        int n = idx >> 7, k = idx & 127;
        const float* W = (j == 0) ? Wa : (j == 1) ? Wb : Wc;
        float v = W[k * 128 + n];
        unsigned short h = f2bf(v);
        WTh[i] = h;
        WTl[i] = f2bf(v - bf2f(h));
    }
}

// ---------------- bf16x3 MFMA GEMM: out = (X @ W) * dinv ----------------
// X: fp32 [N][128] (F32IN) or bf16 hi/lo pair. WT pre-split [n][k] bf16.
// Block: 64 rows, 256 thr (4 waves), wave tile 32x64. LDS 52KB -> 3 blk/CU.

template <bool F32IN>
__global__ __launch_bounds__(256) void gemm_mfma(const void* __restrict__ Xin,
                                                 const void* __restrict__ Xlin,
                                                 const unsigned short* __restrict__ WTh,
                                                 const unsigned short* __restrict__ WTl,
                                                 const float* __restrict__ dinv,
                                                 float* __restrict__ out, int N) {
    __shared__ unsigned short xh[64 * 128];   // 16 KB, XOR-swizzled
    __shared__ unsigned short xl[64 * 128];   // 16 KB
    __shared__ unsigned short wh[128 * 40];   // 10 KB (k-slice, rows padded to 40)
    __shared__ unsigned short wl[128 * 40];   // 10 KB
    int tid = threadIdx.x;
    int lane = tid & 63, wv = tid >> 6;
    int row0 = blockIdx.x * 64;

    #pragma unroll
    for (int i = 0; i < 4; ++i) {
        int id = i * 256 + tid;
        int r = id >> 4, kc = id & 15;
        uint4 vh = make_uint4(0, 0, 0, 0), vl = make_uint4(0, 0, 0, 0);
        if (row0 + r < N) {
            if constexpr (F32IN) {
                const float* Xf = (const float*)Xin;
                float4 a = *(const float4*)(Xf + (size_t)(row0 + r) * 128 + kc * 8);
                float4 b = *(const float4*)(Xf + (size_t)(row0 + r) * 128 + kc * 8 + 4);
                unsigned short h0 = f2bf(a.x), h1 = f2bf(a.y), h2 = f2bf(a.z), h3 = f2bf(a.w);
                unsigned short h4 = f2bf(b.x), h5 = f2bf(b.y), h6 = f2bf(b.z), h7 = f2bf(b.w);
                vh = make_uint4((unsigned)h0 | ((unsigned)h1 << 16),
                                (unsigned)h2 | ((unsigned)h3 << 16),
                                (unsigned)h4 | ((unsigned)h5 << 16),
                                (unsigned)h6 | ((unsigned)h7 << 16));
                vl = make_uint4((unsigned)f2bf(a.x - bf2f(h0)) | ((unsigned)f2bf(a.y - bf2f(h1)) << 16),
                                (unsigned)f2bf(a.z - bf2f(h2)) | ((unsigned)f2bf(a.w - bf2f(h3)) << 16),
                                (unsigned)f2bf(b.x - bf2f(h4)) | ((unsigned)f2bf(b.y - bf2f(h5)) << 16),
                                (unsigned)f2bf(b.z - bf2f(h6)) | ((unsigned)f2bf(b.w - bf2f(h7)) << 16));
            } else {
                vh = *(const uint4*)&((const unsigned*)Xin)[(size_t)(row0 + r) * 64 + kc * 4];
                vl = *(const uint4*)&((const unsigned*)Xlin)[(size_t)(row0 + r) * 64 + kc * 4];
            }
        }
        int off = r * 128 + ((kc * 8) ^ ((r & 7) << 3));
        *(uint4*)&xh[off] = vh;
        *(uint4*)&xl[off] = vl;
    }

    int mstrip = (wv & 1) * 32;
    int nbase = (wv >> 1) * 64;
    f32x4 acc[2][4] = {};

    for (int ks = 0; ks < 4; ++ks) {
        __syncthreads();   // X ready (ks=0) / previous slice consumed
        // copy pre-split W^T k-slice: 512 uint4 per plane, 2 per thread
        #pragma unroll
        for (int i = 0; i < 2; ++i) {
            int id = i * 256 + tid;        // 0..511
            int n = id >> 2, q = id & 3;   // q: 8-short chunk within 32-k slice
            *(uint4*)&wh[n * 40 + q * 8] =
                *(const uint4*)&WTh[(size_t)n * 128 + ks * 32 + q * 8];
            *(uint4*)&wl[n * 40 + q * 8] =
                *(const uint4*)&WTl[(size_t)n * 128 + ks * 32 + q * 8];
        }
        __syncthreads();

        short8v afh[2], afl[2];
        #pragma unroll
        for (int mt = 0; mt < 2; ++mt) {
            int r = mstrip + mt * 16 + (lane & 15);
            int off = r * 128 + ((ks * 32 + ((lane >> 4) * 8)) ^ ((r & 7) << 3));
            afh[mt] = *(const short8v*)&xh[off];
            afl[mt] = *(const short8v*)&xl[off];
        }
        #pragma unroll
        for (int nt = 0; nt < 4; ++nt) {
            int c = nbase + nt * 16 + (lane & 15);
            int boff = c * 40 + (lane >> 4) * 8;
            short8v bfh = *(const short8v*)&wh[boff];
            short8v bfl = *(const short8v*)&wl[boff];
            #pragma unroll
            for (int mt = 0; mt < 2; ++mt) {
                acc[mt][nt] = __builtin_amdgcn_mfma_f32_16x16x32_bf16(afh[mt], bfh, acc[mt][nt], 0, 0, 0);
                acc[mt][nt] = __builtin_amdgcn_mfma_f32_16x16x32_bf16(afh[mt], bfl, acc[mt][nt], 0, 0, 0);
                acc[mt][nt] = __builtin_amdgcn_mfma_f32_16x16x32_bf16(afl[mt], bfh, acc[mt][nt], 0, 0, 0);
            }
        }
    }

    // C/D layout: col=lane&15, row=(lane>>4)*4+reg  [m89]
    #pragma unroll
    for (int mt = 0; mt < 2; ++mt) {
        #pragma unroll
        for (int i = 0; i < 4; ++i) {
            int r = row0 + mstrip + mt * 16 + (lane >> 4) * 4 + i;
            if (r < N) {
                float dv = dinv[r];
                #pragma unroll
                for (int nt = 0; nt < 4; ++nt) {
                    int cg = nbase + nt * 16 + (lane & 15);
                    out[(size_t)r * 128 + cg] = acc[mt][nt][i] * dv;
                }
            }
        }
    }
}

// layer 4: X (bf16 hi/lo) @ W4 [128][16] -> out [N][16] fp32, scaled by dinv
__global__ __launch_bounds__(256) void gemm16(const unsigned* __restrict__ Xh,
                                              const unsigned* __restrict__ Xl,
                                              const float* __restrict__ W,
                                              const float* __restrict__ dinv,
                                              float* __restrict__ out, int N) {
    __shared__ float xs[64][128];
    __shared__ float ws4[128][16];
    int tid = threadIdx.x;
    int row0 = blockIdx.x * 64;

    #pragma unroll
    for (int i = 0; i < 2; ++i)
        ((float4*)ws4)[i * 256 + tid] = ((const float4*)W)[i * 256 + tid];

    #pragma unroll
    for (int i = 0; i < 8; ++i) {
        int id = i * 256 + tid;
        int r = id >> 5, c4 = id & 31;
        float4 v = make_float4(0.f, 0.f, 0.f, 0.f);
        if (row0 + r < N) {
            uint2 hh = *(const uint2*)&Xh[(size_t)(row0 + r) * 64 + c4 * 2];
            uint2 ll = *(const uint2*)&Xl[(size_t)(row0 + r) * 64 + c4 * 2];
            v.x = bf2f(hh.x & 0xffffu) + bf2f(ll.x & 0xffffu);
            v.y = bf2f(hh.x >> 16) + bf2f(ll.x >> 16);
            v.z = bf2f(hh.y & 0xffffu) + bf2f(ll.y & 0xffffu);
            v.w = bf2f(hh.y >> 16) + bf2f(ll.y >> 16);
        }
        *(float4*)&xs[r][c4 * 4] = v;
    }
    __syncthreads();

    int ty = tid >> 4, tx = tid & 15;
    float acc[4] = {};
    #pragma unroll 4
    for (int k = 0; k < 128; ++k) {
        float wvv = ws4[k][tx];
        #pragma unroll
        for (int i = 0; i < 4; ++i)
            acc[i] = fmaf(xs[ty * 4 + i][k], wvv, acc[i]);
    }
    #pragma unroll
    for (int i = 0; i < 4; ++i) {
        int r = row0 + ty * 4 + i;
        if (r < N) out[(size_t)r * 16 + tx] = acc[i] * dinv[r];
    }
}

// ---------------- aggregation: one wave per node, 8 gathers in flight ----------------

template <int ACT>
__global__ __launch_bounds__(256) void agg128(const float* __restrict__ HS,
                                              const int* __restrict__ rp,
                                              const int* __restrict__ csr,
                                              const float* __restrict__ dinv,
                                              const float* __restrict__ b,
                                              unsigned* __restrict__ Xh,
                                              unsigned* __restrict__ Xl, int N) {
    int wid = threadIdx.x >> 6, lane = threadIdx.x & 63;
    int n = blockIdx.x * 4 + wid;
    if (n >= N) return;
    const float2* H2 = (const float2*)HS;
    float2 a0 = H2[(size_t)n * 64 + lane];  // self term
    float2 a1 = make_float2(0.f, 0.f), a2 = a1, a3 = a1;
    float2 a4 = a1, a5 = a1, a6 = a1, a7 = a1;
    int e = rp[n], end = rp[n + 1];
    for (; e + 8 <= end; e += 8) {
        int s0 = csr[e], s1 = csr[e + 1], s2 = csr[e + 2], s3 = csr[e + 3];
        int s4 = csr[e + 4], s5 = csr[e + 5], s6 = csr[e + 6], s7 = csr[e + 7];
        float2 v0 = H2[(size_t)s0 * 64 + lane];
        float2 v1 = H2[(size_t)s1 * 64 + lane];
        float2 v2 = H2[(size_t)s2 * 64 + lane];
        float2 v3 = H2[(size_t)s3 * 64 + lane];
        float2 v4 = H2[(size_t)s4 * 64 + lane];
        float2 v5 = H2[(size_t)s5 * 64 + lane];
        float2 v6 = H2[(size_t)s6 * 64 + lane];
        float2 v7 = H2[(size_t)s7 * 64 + lane];
        a0.x += v0.x; a0.y += v0.y; a1.x += v1.x; a1.y += v1.y;
        a2.x += v2.x; a2.y += v2.y; a3.x += v3.x; a3.y += v3.y;
        a4.x += v4.x; a4.y += v4.y; a5.x += v5.x; a5.y += v5.y;
        a6.x += v6.x; a6.y += v6.y; a7.x += v7.x; a7.y += v7.y;
    }
    if (e + 4 <= end) {
        int s0 = csr[e], s1 = csr[e + 1], s2 = csr[e + 2], s3 = csr[e + 3];
        float2 v0 = H2[(size_t)s0 * 64 + lane];
        float2 v1 = H2[(size_t)s1 * 64 + lane];
        float2 v2 = H2[(size_t)s2 * 64 + lane];
        float2 v3 = H2[(size_t)s3 * 64 + lane];
        a4.x += v0.x; a4.y += v0.y; a5.x += v1.x; a5.y += v1.y;
        a6.x += v2.x; a6.y += v2.y; a7.x += v3.x; a7.y += v3.y;
        e += 4;
    }
    for (; e < end; ++e) {
        int s = csr[e];
        float2 v = H2[(size_t)s * 64 + lane];
        a0.x += v.x; a0.y += v.y;
    }
    float accx = ((a0.x + a1.x) + (a2.x + a3.x)) + ((a4.x + a5.x) + (a6.x + a7.x));
    float accy = ((a0.y + a1.y) + (a2.y + a3.y)) + ((a4.y + a5.y) + (a6.y + a7.y));
    float dv = dinv[n];
    float2 bb = ((const float2*)b)[lane];
    float ox = fmaf(dv, accx, bb.x);
    float oy = fmaf(dv, accy, bb.y);
    if (ACT == 1) { ox = tanhf(ox); oy = tanhf(oy); }
    else if (ACT == 2) {
        ox = ox > 0.f ? ox : 0.01f * ox;
        oy = oy > 0.f ? oy : 0.01f * oy;
    }
    unsigned short h0 = f2bf(ox), h1 = f2bf(oy);
    float l0 = ox - bf2f(h0), l1 = oy - bf2f(h1);
    Xh[(size_t)n * 64 + lane] = (unsigned)h0 | ((unsigned)h1 << 16);
    Xl[(size_t)n * 64 + lane] = (unsigned)f2bf(l0) | ((unsigned)f2bf(l1) << 16);
}

// ---------------- layer-4 aggregation + classifier head ----------------

__global__ __launch_bounds__(256) void final_layer(const float* __restrict__ HS4,
                                                   const int* __restrict__ rp,
                                                   const int* __restrict__ csr,
                                                   const float* __restrict__ dinv,
                                                   const float* __restrict__ b4,
                                                   const float* __restrict__ Wc,
                                                   const float* __restrict__ bc,
                                                   float* __restrict__ out, int N) {
    int wid = threadIdx.x >> 6, lane = threadIdx.x & 63;
    int n = blockIdx.x * 4 + wid;
    if (n >= N) return;
    int f = lane & 15, g = lane >> 4;
    float acc = 0.f;
    int beg = rp[n], end = rp[n + 1];
    for (int e = beg + g; e < end; e += 4)
        acc += HS4[(size_t)csr[e] * 16 + f];
    acc += __shfl_xor(acc, 16);
    acc += __shfl_xor(acc, 32);
    acc += HS4[(size_t)n * 16 + f];
    float t = fmaf(dinv[n], acc, b4[f]);
    t = t > 0.f ? t : 0.01f * t;
    float p = t * Wc[f];
    p += __shfl_xor(p, 1);
    p += __shfl_xor(p, 2);
    p += __shfl_xor(p, 4);
    p += __shfl_xor(p, 8);
    if (lane == 0) {
        float z = p + bc[0];
        out[n] = z > 0.f ? z : expm1f(z);
    }
}

// ---------------- launch ----------------

extern "C" void kernel_launch(void* const* d_in, const int* in_sizes, int n_in,
                              void* d_out, int out_size, void* d_ws, size_t ws_size,
                              hipStream_t stream) {
    const int N = NN, E = NE;
    const float* x  = (const float*)d_in[0];
    const int*   ei = (const int*)d_in[1];
    const float* W1 = (const float*)d_in[2];
    const float* b1 = (const float*)d_in[3];
    const float* W2 = (const float*)d_in[4];
    const float* b2 = (const float*)d_in[5];
    const float* W3 = (const float*)d_in[6];
    const float* b3 = (const float*)d_in[7];
    const float* W4 = (const float*)d_in[8];
    const float* b4 = (const float*)d_in[9];
    const float* Wc = (const float*)d_in[10];
    const float* bc = (const float*)d_in[11];
    float* out = (float*)d_out;
    const int* src = ei;
    const int* dst = ei + E;

    char* p = (char*)d_ws;
    auto carve = [&](size_t bytes) -> char* {
        char* q = p;
        p += (bytes + 255) & ~(size_t)255;
        return q;
    };
    int*            cntP   = (int*)carve((size_t)N * 16 * 4);
    int*            rank   = (int*)carve((size_t)E * 4);
    int*            rowptr = (int*)carve((size_t)(N + 1) * 4);
    float*          dinv   = (float*)carve((size_t)N * 4);
    int*            csr    = (int*)carve((size_t)E * 4);
    int*            locsc  = (int*)carve((size_t)N * 4);
    int*            bsum   = (int*)carve((size_t)64 * 4);
    unsigned short* WTh    = (unsigned short*)carve((size_t)3 * 16384 * 2);
    unsigned short* WTl    = (unsigned short*)carve((size_t)3 * 16384 * 2);
    unsigned*       Xh     = (unsigned*)carve((size_t)N * 64 * 4);
    unsigned*       Xl     = (unsigned*)carve((size_t)N * 64 * 4);
    float*          bufB   = (float*)carve((size_t)N * 128 * 4);

    const int NB = (N + 1023) / 1024;           // 49
    const int sblocks = (E + 255) / 256;        // 3125
    const int wblocks = (3 * 16384) / 256;      // 192

    hipMemsetAsync(cntP, 0, (size_t)N * 16 * 4, stream);
    count_deg_rank<<<sblocks, 256, 0, stream>>>(dst, cntP, rank, E);
    scan1<<<NB, 1024, 0, stream>>>(cntP, locsc, bsum, dinv, N);
    scan3<<<(N + 255) / 256, 256, 0, stream>>>(locsc, bsum, rowptr, N, E, NB);
    scatter_split<<<sblocks + wblocks, 256, 0, stream>>>(src, dst, rowptr, rank, csr, E,
                                                         sblocks, W1, W2, W3, WTh, WTl);

    int gblocks = (N + 63) / 64;
    int ablocks = (N + 3) / 4;

    gemm_mfma<true><<<gblocks, 256, 0, stream>>>(x, nullptr, WTh, WTl, dinv, bufB, N);
    agg128<0><<<ablocks, 256, 0, stream>>>(bufB, rowptr, csr, dinv, b1, Xh, Xl, N);
    gemm_mfma<false><<<gblocks, 256, 0, stream>>>(Xh, Xl, WTh + 16384, WTl + 16384, dinv, bufB, N);
    agg128<1><<<ablocks, 256, 0, stream>>>(bufB, rowptr, csr, dinv, b2, Xh, Xl, N);
    gemm_mfma<false><<<gblocks, 256, 0, stream>>>(Xh, Xl, WTh + 32768, WTl + 32768, dinv, bufB, N);
    agg128<2><<<ablocks, 256, 0, stream>>>(bufB, rowptr, csr, dinv, b3, Xh, Xl, N);
    gemm16<<<gblocks, 256, 0, stream>>>(Xh, Xl, W4, dinv, bufB, N);
    final_layer<<<ablocks, 256, 0, stream>>>(bufB, rowptr, csr, dinv, b4, Wc, bc, out, N);
}